// Round 14
// baseline (1260.641 us; speedup 1.0000x reference)
//
#include <hip/hip_runtime.h>
#include <cstdint>

#define DEV __device__ __forceinline__

typedef __bf16 bf16x8 __attribute__((ext_vector_type(8)));
typedef float f32x4 __attribute__((ext_vector_type(4)));

DEV uint16_t f2bf(float f) {
  uint32_t u = __float_as_uint(f);
  u += 0x7FFFu + ((u >> 16) & 1u);
  return (uint16_t)(u >> 16);
}
DEV float bf2f(uint16_t h) { return __uint_as_float(((uint32_t)h) << 16); }

DEV void gload16(const void* g, void* l) {
  __builtin_amdgcn_global_load_lds((const __attribute__((address_space(1))) void*)g,
                                   (__attribute__((address_space(3))) void*)l, 16, 0, 0);
}

template <int N> DEV void waitcnt_vm() {
  if constexpr (N == 0) asm volatile("s_waitcnt vmcnt(0)" ::: "memory");
  else if constexpr (N == 3) asm volatile("s_waitcnt vmcnt(3)" ::: "memory");
  else if constexpr (N == 4) asm volatile("s_waitcnt vmcnt(4)" ::: "memory");
  else static_assert(N == 0 || N == 3 || N == 4, "unsupported vmcnt");
}

// fast GELU (tanh form): max abs err vs erf-GELU ~3e-3
DEV float gelu_f(float v) {
  float u = v * (0.7978845608f + 0.0356774081f * v * v);
  return v / (1.f + __expf(-2.f * u));
}

// ---------------- LayerNorm over C=768, fp32 in -> bf16 out ----------------
__global__ __launch_bounds__(256) void ln768(const float* __restrict__ x,
                                             const float* __restrict__ w,
                                             const float* __restrict__ b,
                                             uint16_t* __restrict__ out) {
  const size_t row = blockIdx.x;
  const float* xr = x + row * 768;
  const int t = threadIdx.x;
  float v0 = xr[t], v1 = xr[t + 256], v2 = xr[t + 512];
  float s = v0 + v1 + v2;
  float s2 = v0 * v0 + v1 * v1 + v2 * v2;
#pragma unroll
  for (int o = 32; o; o >>= 1) {
    s += __shfl_down(s, o);
    s2 += __shfl_down(s2, o);
  }
  __shared__ float sh[8];
  if ((t & 63) == 0) { sh[t >> 6] = s; sh[4 + (t >> 6)] = s2; }
  __syncthreads();
  s = sh[0] + sh[1] + sh[2] + sh[3];
  s2 = sh[4] + sh[5] + sh[6] + sh[7];
  const float mu = s * (1.f / 768.f);
  const float var = s2 * (1.f / 768.f) - mu * mu;
  const float rstd = rsqrtf(var + 1e-6f);
  uint16_t* orow = out + row * 768;
  orow[t]       = f2bf((v0 - mu) * rstd * w[t] + b[t]);
  orow[t + 256] = f2bf((v1 - mu) * rstd * w[t + 256] + b[t + 256]);
  orow[t + 512] = f2bf((v2 - mu) * rstd * w[t + 512] + b[t + 512]);
}

// -------- batched transpose fp32 [R,Cc] -> bf16 [Cc,R] for all 4 weights ----
__global__ __launch_bounds__(256) void transpose_all(
    const float* __restrict__ w0, const float* __restrict__ w1,
    const float* __restrict__ w2, const float* __restrict__ w3,
    uint16_t* __restrict__ o0, uint16_t* __restrict__ o1,
    uint16_t* __restrict__ o2, uint16_t* __restrict__ o3) {
  int bid = blockIdx.x;
  const float* in;
  uint16_t* outp;
  int gx, ldin, ldout;
  if (bid < 1728) { in = w0; outp = o0; gx = 72; ldin = 2304; ldout = 768; }
  else if (bid < 2304) { bid -= 1728; in = w1; outp = o1; gx = 24; ldin = 768; ldout = 768; }
  else if (bid < 4608) { bid -= 2304; in = w2; outp = o2; gx = 96; ldin = 3072; ldout = 768; }
  else { bid -= 4608; in = w3; outp = o3; gx = 24; ldin = 768; ldout = 3072; }
  const int bx = bid % gx, by = bid / gx;

  __shared__ float tile[32][33];
  const int tx = threadIdx.x, ty = threadIdx.y;
  const size_t x = (size_t)bx * 32 + tx;
  const size_t y = (size_t)by * 32 + ty;
#pragma unroll
  for (int j = 0; j < 4; ++j) tile[ty + j * 8][tx] = in[(y + j * 8) * ldin + x];
  __syncthreads();
  const size_t x2 = (size_t)by * 32 + tx;
  const size_t y2 = (size_t)bx * 32 + ty;
#pragma unroll
  for (int j = 0; j < 4; ++j) outp[(y2 + j * 8) * ldout + x2] = f2bf(tile[tx][ty + j * 8]);
}

// -------- colsum of E, stage 1: 256 blocks -> partial[32][512] --------------
__global__ __launch_bounds__(256) void colsumP(const float* __restrict__ Ek,
                                               const float* __restrict__ Ev,
                                               float* __restrict__ partial) {
  const int b = blockIdx.x;
  const int kt = b & 7, nc = b >> 3;
  const float* src = (kt < 4) ? Ek : Ev;
  const int kbase = (kt & 3) * 64;
  const int kk = threadIdx.x & 63, s = threadIdx.x >> 6;
  float sum = 0.f;
#pragma unroll 4
  for (int i = 0; i < 64; ++i)
    sum += src[(size_t)(nc * 256 + s * 64 + i) * 256 + kbase + kk];
  __shared__ float red[4][64];
  red[s][kk] = sum;
  __syncthreads();
  if (s == 0) {
    const int cg = (kt >= 4 ? 256 : 0) + kbase + kk;
    partial[nc * 512 + cg] = (red[0][kk] + red[1][kk]) + (red[2][kk] + red[3][kk]);
  }
}

// -------- colsum stage 2: reduce 32 partials -> colsum[512] --------------
__global__ __launch_bounds__(256) void colsumR(const float* __restrict__ partial,
                                               float* __restrict__ colsum) {
  const int k = blockIdx.x * 256 + threadIdx.x;
  float s = 0.f;
#pragma unroll
  for (int nc = 0; nc < 32; ++nc) s += partial[nc * 512 + k];
  colsum[k] = s;
}

// ======== hkv gather TN: part[ns][b][k][c] = sum_{n in stripe} E[n,k] h[b][n,c]
__global__ __launch_bounds__(256) void hkv_tn(const float* __restrict__ Ek,
                                              const float* __restrict__ Ev,
                                              const uint16_t* __restrict__ h,
                                              float* __restrict__ part) {
  const int bid = blockIdx.x;
  const int wg = (bid & 7) * 96 + (bid >> 3);
  const int inner = wg & 31;
  const int kt = inner & 7, ns = inner >> 3;
  const int rest = wg >> 5;
  const int ct = rest % 12, b = rest / 12;
  const int k0 = kt * 64, c0 = ct * 64, nsb = ns * 2048;

  const float* Esrc = (k0 < 256) ? Ek : Ev;
  const int kc = k0 & 255;

  const int tid = threadIdx.x, wave = tid >> 6, lane = tid & 63;
  const int l16 = lane & 15, lhi = lane >> 4;
  const int wm = wave >> 1, wn = wave & 1;

  f32x4 acc[2][2];
#pragma unroll
  for (int m = 0; m < 2; ++m)
#pragma unroll
    for (int n = 0; n < 2; ++n) acc[m][n] = f32x4{0.f, 0.f, 0.f, 0.f};

  const int krow0 = kc + wm * 32 + l16;
  const uint16_t* Hb = h + ((size_t)b * 8192 + nsb + lhi * 8) * 768 + c0 + wn * 32 + l16;

  for (int n0 = 0; n0 < 2048; n0 += 32) {
    bf16x8 ef[2];
#pragma unroll
    for (int m = 0; m < 2; ++m) {
      const float* p = Esrc + (size_t)(nsb + n0 + lhi * 8) * 256 + krow0 + m * 16;
      union { bf16x8 v; uint16_t u[8]; } tu;
#pragma unroll
      for (int j = 0; j < 8; ++j) tu.u[j] = f2bf(p[(size_t)j * 256]);
      ef[m] = tu.v;
    }
    bf16x8 vf[2];
#pragma unroll
    for (int nf = 0; nf < 2; ++nf) {
      const uint16_t* p = Hb + (size_t)n0 * 768 + nf * 16;
      union { bf16x8 v; uint16_t u[8]; } tu;
#pragma unroll
      for (int j = 0; j < 8; ++j) tu.u[j] = p[(size_t)j * 768];
      vf[nf] = tu.v;
    }
#pragma unroll
    for (int m = 0; m < 2; ++m)
#pragma unroll
      for (int nf = 0; nf < 2; ++nf)
        acc[m][nf] = __builtin_amdgcn_mfma_f32_16x16x32_bf16(ef[m], vf[nf], acc[m][nf], 0, 0, 0);
  }

  float* outp = part + ((size_t)ns * 2 + b) * 393216;
#pragma unroll
  for (int m = 0; m < 2; ++m)
#pragma unroll
    for (int nf = 0; nf < 2; ++nf)
#pragma unroll
      for (int r = 0; r < 4; ++r)
        outp[(size_t)(k0 + wm * 32 + m * 16 + lhi * 4 + r) * 768 + c0 + wn * 32 + nf * 16 + l16] =
            acc[m][nf][r];
}

// -------- reduce 4 n-stripe fp32 partials -> bf16 hkv [b][512][768]
__global__ __launch_bounds__(256) void kv_reduce(const float* __restrict__ part,
                                                 uint16_t* __restrict__ hkv) {
  const int i = blockIdx.x * 256 + threadIdx.x;
  float s = part[i] + part[786432 + i] + part[2 * 786432 + i] + part[3 * 786432 + i];
  hkv[i] = f2bf(s);
}

// ---------------- small NT GEMM with z-batching (kvW step) ----------
template <int BM, int BN>
__global__ __launch_bounds__(256) void gemm_kvw(
    const uint16_t* __restrict__ Abase, const uint16_t* __restrict__ Bbase,
    uint16_t* __restrict__ Cbase, const float* __restrict__ bias,
    const float* __restrict__ rowscale, uint16_t* __restrict__ vpt,
    int Kd, int lda, int ldb, int ldc,
    int zdiv, size_t sAhi, size_t sAlo, size_t sBhi, size_t sBlo,
    size_t sChi, size_t sClo, int rs_z, int bias_z) {
  const int z = blockIdx.z;
  const int zhi = z / zdiv, zlo = z - zhi * zdiv;
  const uint16_t* A = Abase + zhi * sAhi + zlo * sAlo;
  const uint16_t* B = Bbase + zhi * sBhi + zlo * sBlo;
  const size_t coff = zhi * sChi + zlo * sClo;

  constexpr int WTM = BM / 2, WTN = BN / 2;
  constexpr int FM = WTM / 16, FN = WTN / 16;
  const int tid = threadIdx.x;
  const int wave = tid >> 6, lane = tid & 63;
  const int wm = wave >> 1, wn = wave & 1;
  const int l16 = lane & 15, lhi = lane >> 4;

  __shared__ __align__(16) uint16_t sA[BM * 32];
  __shared__ __align__(16) uint16_t sB[BN * 32];

  f32x4 acc[FM][FN];
#pragma unroll
  for (int m = 0; m < FM; ++m)
#pragma unroll
    for (int n = 0; n < FN; ++n) acc[m][n] = f32x4{0.f, 0.f, 0.f, 0.f};

  const int row0 = blockIdx.x * BM;
  const int col0 = blockIdx.y * BN;
  const int rr = tid >> 2, cq = tid & 3;

  for (int k0 = 0; k0 < Kd; k0 += 32) {
    __syncthreads();
#pragma unroll
    for (int is = 0; is < BM / 64; ++is) {
      const uint16_t* g = A + (size_t)(row0 + is * 64 + rr) * lda + k0 + cq * 8;
      gload16(g, &sA[is * 2048 + tid * 8]);
    }
#pragma unroll
    for (int is = 0; is < BN / 64; ++is) {
      const uint16_t* g = B + (size_t)(col0 + is * 64 + rr) * ldb + k0 + cq * 8;
      gload16(g, &sB[is * 2048 + tid * 8]);
    }
    __syncthreads();

    bf16x8 af[FM], bq[FN];
#pragma unroll
    for (int m = 0; m < FM; ++m)
      af[m] = *(const bf16x8*)(&sA[(wm * WTM + m * 16 + l16) * 32 + lhi * 8]);
#pragma unroll
    for (int n = 0; n < FN; ++n)
      bq[n] = *(const bf16x8*)(&sB[(wn * WTN + n * 16 + l16) * 32 + lhi * 8]);
#pragma unroll
    for (int m = 0; m < FM; ++m)
#pragma unroll
      for (int n = 0; n < FN; ++n)
        acc[m][n] = __builtin_amdgcn_mfma_f32_16x16x32_bf16(af[m], bq[n], acc[m][n], 0, 0, 0);
  }

#pragma unroll
  for (int m = 0; m < FM; ++m) {
#pragma unroll
    for (int n = 0; n < FN; ++n) {
      const int col = col0 + wn * WTN + n * 16 + l16;
      const float bv = bias[zlo * bias_z + col];
#pragma unroll
      for (int r = 0; r < 4; ++r) {
        const int row = row0 + wm * WTM + m * 16 + lhi * 4 + r;
        float v = acc[m][n][r] + rowscale[zlo * rs_z + row] * bv;
        if (zlo == 1) {
          vpt[(size_t)zhi * 196608 + (size_t)col * 256 + row] = f2bf(v);
        } else {
          Cbase[coff + (size_t)row * ldc + col] = f2bf(v);
        }
      }
    }
  }
}

// ======== fused attention: one (qtile64, b, h) block (verified) ========
__global__ __launch_bounds__(256, 3) void attn_fused(
    const uint16_t* __restrict__ q, const uint16_t* __restrict__ kproj,
    const uint16_t* __restrict__ vprojT, uint16_t* __restrict__ o) {
  const int bh = blockIdx.y;
  const int b = bh / 12, h = bh % 12;
  const int n0 = blockIdx.x * 64;
  const int tid = threadIdx.x, wave = tid >> 6, lane = tid & 63;
  const int l16 = lane & 15, lhi = lane >> 4;
  const int wm = wave >> 1, wn = wave & 1;

  __shared__ __align__(16) uint16_t sP[64 * 256];
  __shared__ float redm[2][64], reds[2][64], recs[64];

  const uint16_t* Kp = kproj + (size_t)b * 196608 + h * 64;
  const uint16_t* Qp = q + ((size_t)b * 8192 + n0) * 768 + h * 64;
  const uint16_t* Vp = vprojT + ((size_t)b * 768 + h * 64) * 256;

  f32x4 st[8][2];
#pragma unroll
  for (int m = 0; m < 8; ++m)
#pragma unroll
    for (int nf = 0; nf < 2; ++nf) st[m][nf] = f32x4{0.f, 0.f, 0.f, 0.f};
#pragma unroll
  for (int ks = 0; ks < 2; ++ks) {
    bf16x8 kf[8], qf[2];
#pragma unroll
    for (int m = 0; m < 8; ++m) {
      const int kvi = wm * 128 + m * 16 + l16;
      kf[m] = *(const bf16x8*)(Kp + (size_t)kvi * 768 + ks * 32 + lhi * 8);
    }
#pragma unroll
    for (int nf = 0; nf < 2; ++nf) {
      const int n = wn * 32 + nf * 16 + l16;
      qf[nf] = *(const bf16x8*)(Qp + (size_t)n * 768 + ks * 32 + lhi * 8);
    }
#pragma unroll
    for (int m = 0; m < 8; ++m)
#pragma unroll
      for (int nf = 0; nf < 2; ++nf)
        st[m][nf] = __builtin_amdgcn_mfma_f32_16x16x32_bf16(kf[m], qf[nf], st[m][nf], 0, 0, 0);
  }

  float pmax[2] = {-50.f, -50.f};
#pragma unroll
  for (int m = 0; m < 8; ++m)
#pragma unroll
    for (int nf = 0; nf < 2; ++nf)
#pragma unroll
      for (int r = 0; r < 4; ++r) {
        float v = fminf(fmaxf(st[m][nf][r] * 0.125f, -50.f), 50.f);
        st[m][nf][r] = v;
        pmax[nf] = fmaxf(pmax[nf], v);
      }
#pragma unroll
  for (int nf = 0; nf < 2; ++nf) {
    pmax[nf] = fmaxf(pmax[nf], __shfl_xor(pmax[nf], 16));
    pmax[nf] = fmaxf(pmax[nf], __shfl_xor(pmax[nf], 32));
  }
  if (lhi == 0) {
#pragma unroll
    for (int nf = 0; nf < 2; ++nf) redm[wm][wn * 32 + nf * 16 + l16] = pmax[nf];
  }
  __syncthreads();
  float M[2];
#pragma unroll
  for (int nf = 0; nf < 2; ++nf) {
    const int col = wn * 32 + nf * 16 + l16;
    M[nf] = fmaxf(redm[0][col], redm[1][col]);
  }

  float psum[2] = {0.f, 0.f};
#pragma unroll
  for (int m = 0; m < 8; ++m) {
#pragma unroll
    for (int nf = 0; nf < 2; ++nf) {
      float e0 = __expf(st[m][nf][0] - M[nf]);
      float e1 = __expf(st[m][nf][1] - M[nf]);
      float e2 = __expf(st[m][nf][2] - M[nf]);
      float e3 = __expf(st[m][nf][3] - M[nf]);
      psum[nf] += (e0 + e1) + (e2 + e3);
      uint2 pk;
      pk.x = (uint32_t)f2bf(e0) | ((uint32_t)f2bf(e1) << 16);
      pk.y = (uint32_t)f2bf(e2) | ((uint32_t)f2bf(e3) << 16);
      const int n = wn * 32 + nf * 16 + l16;
      const int kvb2 = (wm * 128 + m * 16 + lhi * 4) * 2;
      *(uint2*)((char*)sP + n * 512 + (kvb2 ^ ((n & 7) << 4))) = pk;
    }
  }
#pragma unroll
  for (int nf = 0; nf < 2; ++nf) {
    psum[nf] += __shfl_xor(psum[nf], 16);
    psum[nf] += __shfl_xor(psum[nf], 32);
  }
  if (lhi == 0) {
#pragma unroll
    for (int nf = 0; nf < 2; ++nf) reds[wm][wn * 32 + nf * 16 + l16] = psum[nf];
  }
  __syncthreads();
  if (wm == 0 && lhi == 0) {
#pragma unroll
    for (int nf = 0; nf < 2; ++nf) {
      const int col = wn * 32 + nf * 16 + l16;
      recs[col] = 1.f / (reds[0][col] + reds[1][col]);
    }
  }
  __syncthreads();

  f32x4 pacc[2][2];
#pragma unroll
  for (int mf = 0; mf < 2; ++mf)
#pragma unroll
    for (int nf = 0; nf < 2; ++nf) pacc[mf][nf] = f32x4{0.f, 0.f, 0.f, 0.f};
#pragma unroll
  for (int ks = 0; ks < 8; ++ks) {
    bf16x8 pa[2], vb[2];
#pragma unroll
    for (int mf = 0; mf < 2; ++mf) {
      const int n = wm * 32 + mf * 16 + l16;
      pa[mf] = *(const bf16x8*)((char*)sP + n * 512 + ((ks * 64 + lhi * 16) ^ ((n & 7) << 4)));
    }
#pragma unroll
    for (int nf = 0; nf < 2; ++nf) {
      const int d = wn * 32 + nf * 16 + l16;
      vb[nf] = *(const bf16x8*)(Vp + (size_t)d * 256 + ks * 32 + lhi * 8);
    }
#pragma unroll
    for (int mf = 0; mf < 2; ++mf)
#pragma unroll
      for (int nf = 0; nf < 2; ++nf)
        pacc[mf][nf] = __builtin_amdgcn_mfma_f32_16x16x32_bf16(pa[mf], vb[nf], pacc[mf][nf], 0, 0, 0);
  }
  uint16_t* orow = o + ((size_t)b * 8192 + n0) * 768 + h * 64;
#pragma unroll
  for (int mf = 0; mf < 2; ++mf) {
#pragma unroll
    for (int r = 0; r < 4; ++r) {
      const int n = wm * 32 + mf * 16 + lhi * 4 + r;
      const float inv = recs[n];
#pragma unroll
      for (int nf = 0; nf < 2; ++nf) {
        const int d = wn * 32 + nf * 16 + l16;
        orow[(size_t)n * 768 + d] = f2bf(pacc[mf][nf][r] * inv);
      }
    }
  }
}

// ======== gemm128: 128x128 NT, BK=32, 3 bufs (48 KB), 3 blocks/CU ========
template <bool OUTBF, bool HASBIAS, bool DOGELU, bool HASRES>
__global__ __launch_bounds__(256, 3) void gemm128(
    const uint16_t* __restrict__ A, const uint16_t* __restrict__ B,
    void* __restrict__ Cbase, const float* __restrict__ bias,
    const float* __restrict__ res, int Kd, int lda, int ldb, int ldc) {
  constexpr int PL = 4096;
  __shared__ __align__(16) uint16_t lds[3 * 2 * PL];

  const int nn = gridDim.y;
  const int nwg = gridDim.x * gridDim.y;
  const int bid = blockIdx.y * gridDim.x + blockIdx.x;
  const int q = nwg >> 3, r8 = nwg & 7, xcd = bid & 7, idx = bid >> 3;
  const int wg = (xcd < r8 ? xcd * (q + 1) : r8 * (q + 1) + (xcd - r8) * q) + idx;
  const int bm = wg / nn, bn = wg % nn;
  const int row0 = bm * 128, col0 = bn * 128;

  const int tid = threadIdx.x;
  const int wave = tid >> 6, lane = tid & 63;
  const int wm = wave >> 1, wn = wave & 1;
  const int l16 = lane & 15, lhi = lane >> 4;
  const int srow = tid >> 2, sq = tid & 3;

  auto stage = [&](int buf, int t) {
    const int k0 = t * 32;
    uint16_t* sa = lds + buf * 2 * PL;
#pragma unroll
    for (int j = 0; j < 2; ++j) {
      const int rw = j * 64 + srow;
      const int sl = sq ^ ((rw >> 1) & 3);
      gload16(A + (size_t)(row0 + rw) * lda + k0 + sl * 8, sa + rw * 32 + sq * 8);
    }
#pragma unroll
    for (int j = 0; j < 2; ++j) {
      const int rw = j * 64 + srow;
      const int sl = sq ^ ((rw >> 1) & 3);
      gload16(B + (size_t)(col0 + rw) * ldb + k0 + sl * 8, sa + PL + rw * 32 + sq * 8);
    }
  };

  f32x4 acc[4][4];
#pragma unroll
  for (int m = 0; m < 4; ++m)
#pragma unroll
    for (int n = 0; n < 4; ++n) acc[m][n] = f32x4{0.f, 0.f, 0.f, 0.f};

  const int NT = Kd >> 5;
  stage(0, 0);
  stage(1, 1);

  for (int t = 0; t < NT; ++t) {
    if (t < NT - 1) waitcnt_vm<4>();
    else waitcnt_vm<0>();
    __builtin_amdgcn_s_barrier();
    asm volatile("" ::: "memory");
    if (t + 2 < NT) stage((t + 2) % 3, t + 2);

    const uint16_t* sa = lds + (t % 3) * 2 * PL;
    const uint16_t* sb = sa + PL;
    bf16x8 af[4], bfv[4];
#pragma unroll
    for (int n = 0; n < 4; ++n) {
      const int rw = wn * 64 + n * 16 + l16;
      bfv[n] = *(const bf16x8*)(sb + rw * 32 + (lhi ^ ((rw >> 1) & 3)) * 8);
    }
#pragma unroll
    for (int m = 0; m < 4; ++m) {
      const int rw = wm * 64 + m * 16 + l16;
      af[m] = *(const bf16x8*)(sa + rw * 32 + (lhi ^ ((rw >> 1) & 3)) * 8);
    }
    __builtin_amdgcn_s_setprio(1);
#pragma unroll
    for (int m = 0; m < 4; ++m)
#pragma unroll
      for (int n = 0; n < 4; ++n)
        acc[m][n] = __builtin_amdgcn_mfma_f32_16x16x32_bf16(af[m], bfv[n], acc[m][n], 0, 0, 0);
    __builtin_amdgcn_s_setprio(0);
  }

  float* Cf = (float*)Cbase;
  uint16_t* Cb = (uint16_t*)Cbase;
#pragma unroll
  for (int m = 0; m < 4; ++m) {
#pragma unroll
    for (int n = 0; n < 4; ++n) {
      const int col = col0 + wn * 64 + n * 16 + l16;
      float bv = 0.f;
      if (HASBIAS) bv = bias[col];
#pragma unroll
      for (int r = 0; r < 4; ++r) {
        const int row = row0 + wm * 64 + m * 16 + lhi * 4 + r;
        float v = acc[m][n][r] + bv;
        if (DOGELU) v = gelu_f(v);
        const size_t cidx = (size_t)row * ldc + col;
        if (HASRES) v += res[cidx];
        if (OUTBF) Cb[cidx] = f2bf(v);
        else Cf[cidx] = v;
      }
    }
  }
}

// ======== gemm1b: 128x128 NT, BK=32, SINGLE buffer (16 KB), max occupancy
// (7 blocks/CU target), m97-style 2-barrier loop, XOR swizzle, XCD swizzle. ===
template <bool OUTBF, bool HASBIAS, bool DOGELU, bool HASRES>
__global__ __launch_bounds__(256, 7) void gemm1b(
    const uint16_t* __restrict__ A, const uint16_t* __restrict__ B,
    void* __restrict__ Cbase, const float* __restrict__ bias,
    const float* __restrict__ res, int Kd, int lda, int ldb, int ldc) {
  constexpr int PL = 4096;
  __shared__ __align__(16) uint16_t lds[2 * PL];  // 16 KB

  const int nn = gridDim.y;
  const int nwg = gridDim.x * gridDim.y;
  const int bid = blockIdx.y * gridDim.x + blockIdx.x;
  const int q = nwg >> 3, r8 = nwg & 7, xcd = bid & 7, idx = bid >> 3;
  const int wg = (xcd < r8 ? xcd * (q + 1) : r8 * (q + 1) + (xcd - r8) * q) + idx;
  const int bm = wg / nn, bn = wg % nn;
  const int row0 = bm * 128, col0 = bn * 128;

  const int tid = threadIdx.x;
  const int wave = tid >> 6, lane = tid & 63;
  const int wm = wave >> 1, wn = wave & 1;
  const int l16 = lane & 15, lhi = lane >> 4;
  const int srow = tid >> 2, sq = tid & 3;

  f32x4 acc[4][4];
#pragma unroll
  for (int m = 0; m < 4; ++m)
#pragma unroll
    for (int n = 0; n < 4; ++n) acc[m][n] = f32x4{0.f, 0.f, 0.f, 0.f};

  const int NT = Kd >> 5;
  for (int t = 0; t < NT; ++t) {
    const int k0 = t * 32;
    // stage tile t (4 x gload16)
#pragma unroll
    for (int j = 0; j < 2; ++j) {
      const int rw = j * 64 + srow;
      const int sl = sq ^ ((rw >> 1) & 3);
      gload16(A + (size_t)(row0 + rw) * lda + k0 + sl * 8, lds + rw * 32 + sq * 8);
    }
#pragma unroll
    for (int j = 0; j < 2; ++j) {
      const int rw = j * 64 + srow;
      const int sl = sq ^ ((rw >> 1) & 3);
      gload16(B + (size_t)(col0 + rw) * ldb + k0 + sl * 8, lds + PL + rw * 32 + sq * 8);
    }
    __syncthreads();  // drains vmcnt, publishes tile

    bf16x8 af[4], bfv[4];
#pragma unroll
    for (int n = 0; n < 4; ++n) {
      const int rw = wn * 64 + n * 16 + l16;
      bfv[n] = *(const bf16x8*)(lds + PL + rw * 32 + (lhi ^ ((rw >> 1) & 3)) * 8);
    }
#pragma unroll
    for (int m = 0; m < 4; ++m) {
      const int rw = wm * 64 + m * 16 + l16;
      af[m] = *(const bf16x8*)(lds + rw * 32 + (lhi ^ ((rw >> 1) & 3)) * 8);
    }
    __builtin_amdgcn_s_setprio(1);
#pragma unroll
    for (int m = 0; m < 4; ++m)
#pragma unroll
      for (int n = 0; n < 4; ++n)
        acc[m][n] = __builtin_amdgcn_mfma_f32_16x16x32_bf16(af[m], bfv[n], acc[m][n], 0, 0, 0);
    __builtin_amdgcn_s_setprio(0);
    __syncthreads();  // all reads done before next overwrite
  }

  float* Cf = (float*)Cbase;
  uint16_t* Cb = (uint16_t*)Cbase;
#pragma unroll
  for (int m = 0; m < 4; ++m) {
#pragma unroll
    for (int n = 0; n < 4; ++n) {
      const int col = col0 + wn * 64 + n * 16 + l16;
      float bv = 0.f;
      if (HASBIAS) bv = bias[col];
#pragma unroll
      for (int r = 0; r < 4; ++r) {
        const int row = row0 + wm * 64 + m * 16 + lhi * 4 + r;
        float v = acc[m][n][r] + bv;
        if (DOGELU) v = gelu_f(v);
        const size_t cidx = (size_t)row * ldc + col;
        if (HASRES) v += res[cidx];
        if (OUTBF) Cb[cidx] = f2bf(v);
        else Cf[cidx] = v;
      }
    }
  }
}

// ======== gemm512: 256x128 NT, 512 thr / 8 waves (4x2), wave-tile 64x64,
// BK=32, 3 bufs (72 KB), 2 blocks/CU, counted vmcnt(3). ========
template <bool OUTBF, bool HASBIAS, bool DOGELU, bool HASRES>
__global__ __launch_bounds__(512, 4) void gemm512(
    const uint16_t* __restrict__ A, const uint16_t* __restrict__ B,
    void* __restrict__ Cbase, const float* __restrict__ bias,
    const float* __restrict__ res, int Kd, int lda, int ldb, int ldc) {
  constexpr int APL = 8192, BPL = 4096;
  __shared__ __align__(16) uint16_t lds[3 * (APL + BPL)];

  const int nn = gridDim.y;
  const int nwg = gridDim.x * gridDim.y;
  const int bid = blockIdx.y * gridDim.x + blockIdx.x;
  const int q = nwg >> 3, r8 = nwg & 7, xcd = bid & 7, idx = bid >> 3;
  const int wg = (xcd < r8 ? xcd * (q + 1) : r8 * (q + 1) + (xcd - r8) * q) + idx;
  const int bm = wg / nn, bn = wg % nn;
  const int row0 = bm * 256, col0 = bn * 128;

  const int tid = threadIdx.x;
  const int wave = tid >> 6, lane = tid & 63;
  const int wm = wave >> 1, wn = wave & 1;
  const int l16 = lane & 15, lhi = lane >> 4;
  const int srow = tid >> 2, sq = tid & 3;

  auto stage = [&](int buf, int t) {
    const int k0 = t * 32;
    uint16_t* sa = lds + buf * (APL + BPL);
#pragma unroll
    for (int j = 0; j < 2; ++j) {
      const int rw = j * 128 + srow;
      const int sl = sq ^ ((rw >> 1) & 3);
      gload16(A + (size_t)(row0 + rw) * lda + k0 + sl * 8, sa + rw * 32 + sq * 8);
    }
    {
      const int rw = srow;
      const int sl = sq ^ ((rw >> 1) & 3);
      gload16(B + (size_t)(col0 + rw) * ldb + k0 + sl * 8, sa + APL + rw * 32 + sq * 8);
    }
  };

  f32x4 acc[4][4];
#pragma unroll
  for (int m = 0; m < 4; ++m)
#pragma unroll
    for (int n = 0; n < 4; ++n) acc[m][n] = f32x4{0.f, 0.f, 0.f, 0.f};

  const int NT = Kd >> 5;
  stage(0, 0);
  stage(1, 1);

  for (int t = 0; t < NT; ++t) {
    if (t < NT - 1) waitcnt_vm<3>();
    else waitcnt_vm<0>();
    __builtin_amdgcn_s_barrier();
    asm volatile("" ::: "memory");
    if (t + 2 < NT) stage((t + 2) % 3, t + 2);

    const uint16_t* sa = lds + (t % 3) * (APL + BPL);
    const uint16_t* sb = sa + APL;
    bf16x8 af[4], bfv[4];
#pragma unroll
    for (int n = 0; n < 4; ++n) {
      const int rw = wn * 64 + n * 16 + l16;
      bfv[n] = *(const bf16x8*)(sb + rw * 32 + (lhi ^ ((rw >> 1) & 3)) * 8);
    }
#pragma unroll
    for (int m = 0; m < 4; ++m) {
      const int rw = wm * 64 + m * 16 + l16;
      af[m] = *(const bf16x8*)(sa + rw * 32 + (lhi ^ ((rw >> 1) & 3)) * 8);
    }
    __builtin_amdgcn_s_setprio(1);
#pragma unroll
    for (int m = 0; m < 4; ++m)
#pragma unroll
      for (int n = 0; n < 4; ++n)
        acc[m][n] = __builtin_amdgcn_mfma_f32_16x16x32_bf16(af[m], bfv[n], acc[m][n], 0, 0, 0);
    __builtin_amdgcn_s_setprio(0);
  }

  float* Cf = (float*)Cbase;
  uint16_t* Cb = (uint16_t*)Cbase;
#pragma unroll
  for (int m = 0; m < 4; ++m) {
#pragma unroll
    for (int n = 0; n < 4; ++n) {
      const int col = col0 + wn * 64 + n * 16 + l16;
      float bv = 0.f;
      if (HASBIAS) bv = bias[col];
#pragma unroll
      for (int r = 0; r < 4; ++r) {
        const int row = row0 + wm * 64 + m * 16 + lhi * 4 + r;
        float v = acc[m][n][r] + bv;
        if (DOGELU) v = gelu_f(v);
        const size_t cidx = (size_t)row * ldc + col;
        if (HASRES) v += res[cidx];
        if (OUTBF) Cb[cidx] = f2bf(v);
        else Cf[cidx] = v;
      }
    }
  }
}

extern "C" void kernel_launch(void* const* d_in, const int* in_sizes, int n_in,
                              void* d_out, int out_size, void* d_ws, size_t ws_size,
                              hipStream_t stream) {
  const float* x      = (const float*)d_in[0];
  const float* ln1_w  = (const float*)d_in[1];
  const float* ln1_b  = (const float*)d_in[2];
  const float* qkv_w  = (const float*)d_in[3];
  const float* qkv_b  = (const float*)d_in[4];
  const float* Ek     = (const float*)d_in[5];
  const float* Ev     = (const float*)d_in[6];
  const float* proj_w = (const float*)d_in[7];
  const float* proj_b = (const float*)d_in[8];
  const float* ln2_w  = (const float*)d_in[9];
  const float* ln2_b  = (const float*)d_in[10];
  const float* fc1_w  = (const float*)d_in[11];
  const float* fc1_b  = (const float*)d_in[12];
  const float* fc2_w  = (const float*)d_in[13];
  const float* fc2_b  = (const float*)d_in[14];
  float* out = (float*)d_out;

  char* w8 = (char*)d_ws;
  size_t off = 0;
  auto take = [&](size_t bytes) { char* p = w8 + off; off += bytes; return p; };
  uint16_t* qkv_wT  = (uint16_t*)take(2304ull * 768 * 2);
  uint16_t* proj_wT = (uint16_t*)take(768ull * 768 * 2);
  uint16_t* fc1_wT  = (uint16_t*)take(3072ull * 768 * 2);
  uint16_t* fc2_wT  = (uint16_t*)take(768ull * 3072 * 2);
  uint16_t* h_bf    = (uint16_t*)take(16384ull * 768 * 2);
  uint16_t* q_bf    = (uint16_t*)take(16384ull * 768 * 2);
  uint16_t* big     = (uint16_t*)take(100663296ull);           // hkv partials -> fc1 out
  uint16_t* hkv_bf  = (uint16_t*)take(2ull * 512 * 768 * 2);   // [b][512][768]
  uint16_t* kproj   = (uint16_t*)take(2ull * 256 * 768 * 2);   // [b][256][768] (k only)
  uint16_t* vprojT  = (uint16_t*)take(2ull * 768 * 256 * 2);   // [b][768][256]
  uint16_t* o_bf    = (uint16_t*)take(16384ull * 768 * 2);
  float* colsum     = (float*)take(512 * 4);
  float* cpartial   = (float*)take(32 * 512 * 4);
  float* part = (float*)big;  // [4][2][512][768] fp32 = 12.6 MB
  (void)ws_size; (void)in_sizes; (void)n_in; (void)out_size;

  // 1) all weight transposes in ONE launch; parallel colsum of E (2-stage)
  transpose_all<<<6912, dim3(32, 8), 0, stream>>>(
      qkv_w, proj_w, fc1_w, fc2_w, qkv_wT, proj_wT, fc1_wT, fc2_wT);
  colsumP<<<256, 256, 0, stream>>>(Ek, Ev, cpartial);
  colsumR<<<2, 256, 0, stream>>>(cpartial, colsum);
  // 2) LN1 -> h_bf
  ln768<<<16384, 256, 0, stream>>>(x, ln1_w, ln1_b, h_bf);
  // 3) q = h @ Wq + bq
  gemm128<true, true, false, false><<<dim3(128, 6), 256, 0, stream>>>(
      h_bf, qkv_wT, q_bf, qkv_b, nullptr, 768, 768, 768, 768);
  // 4) hkv = [Ek;Ev]^T @ h  (direct gather of fp32 E, 4 n-stripe partials)
  hkv_tn<<<768, 256, 0, stream>>>(Ek, Ev, h_bf, part);
  kv_reduce<<<3072, 256, 0, stream>>>(part, hkv_bf);
  // 5) k_proj = hkv_k @ Wk + colsumEk*bk -> kproj; v_proj transposed -> vprojT
  gemm_kvw<64, 64><<<dim3(4, 12, 4), 256, 0, stream>>>(
      hkv_bf, qkv_wT + 768ull * 768, kproj, qkv_b + 768, colsum, vprojT,
      768, 768, 768, 768,
      2, 512ull * 768, 256ull * 768, 0, 768ull * 768, 196608, 0, 256, 768);
  // 6) fused attention -> o_bf
  attn_fused<<<dim3(128, 24), 256, 0, stream>>>(q_bf, kproj, vprojT, o_bf);
  // 7) x2 = x + o @ proj_w + b -> d_out (fp32)
  gemm128<false, true, false, true><<<dim3(128, 6), 256, 0, stream>>>(
      o_bf, proj_wT, out, proj_b, x, 768, 768, 768, 768);
  // 8) LN2
  ln768<<<16384, 256, 0, stream>>>(out, ln2_w, ln2_b, h_bf);
  // 9) a1 = gelu(h2 @ fc1_w + b) -> big  (gemm512, champion)
  gemm512<true, true, true, false><<<dim3(64, 24), 512, 0, stream>>>(
      h_bf, fc1_wT, big, fc1_b, nullptr, 768, 768, 768, 3072);
  // 10) out = x2 + a1 @ fc2_w + b (in-place residual) — gemm1b EXPERIMENT
  gemm1b<false, true, false, true><<<dim3(128, 6), 256, 0, stream>>>(
      big, fc2_wT, out, fc2_b, out, 3072, 3072, 3072, 768);
}

// Round 15
// 469.272 us; speedup vs baseline: 2.6864x; 2.6864x over previous
//
#include <hip/hip_runtime.h>
#include <cstdint>

#define DEV __device__ __forceinline__

typedef __bf16 bf16x8 __attribute__((ext_vector_type(8)));
typedef float f32x4 __attribute__((ext_vector_type(4)));

DEV uint16_t f2bf(float f) {
  uint32_t u = __float_as_uint(f);
  u += 0x7FFFu + ((u >> 16) & 1u);
  return (uint16_t)(u >> 16);
}
DEV float bf2f(uint16_t h) { return __uint_as_float(((uint32_t)h) << 16); }

DEV void gload16(const void* g, void* l) {
  __builtin_amdgcn_global_load_lds((const __attribute__((address_space(1))) void*)g,
                                   (__attribute__((address_space(3))) void*)l, 16, 0, 0);
}

template <int N> DEV void waitcnt_vm() {
  if constexpr (N == 0) asm volatile("s_waitcnt vmcnt(0)" ::: "memory");
  else if constexpr (N == 3) asm volatile("s_waitcnt vmcnt(3)" ::: "memory");
  else if constexpr (N == 4) asm volatile("s_waitcnt vmcnt(4)" ::: "memory");
  else static_assert(N == 0 || N == 3 || N == 4, "unsupported vmcnt");
}

// fast GELU (tanh form): max abs err vs erf-GELU ~3e-3
DEV float gelu_f(float v) {
  float u = v * (0.7978845608f + 0.0356774081f * v * v);
  return v / (1.f + __expf(-2.f * u));
}

// ---------------- LayerNorm over C=768, fp32 in -> bf16 out ----------------
__global__ __launch_bounds__(256) void ln768(const float* __restrict__ x,
                                             const float* __restrict__ w,
                                             const float* __restrict__ b,
                                             uint16_t* __restrict__ out) {
  const size_t row = blockIdx.x;
  const float* xr = x + row * 768;
  const int t = threadIdx.x;
  float v0 = xr[t], v1 = xr[t + 256], v2 = xr[t + 512];
  float s = v0 + v1 + v2;
  float s2 = v0 * v0 + v1 * v1 + v2 * v2;
#pragma unroll
  for (int o = 32; o; o >>= 1) {
    s += __shfl_down(s, o);
    s2 += __shfl_down(s2, o);
  }
  __shared__ float sh[8];
  if ((t & 63) == 0) { sh[t >> 6] = s; sh[4 + (t >> 6)] = s2; }
  __syncthreads();
  s = sh[0] + sh[1] + sh[2] + sh[3];
  s2 = sh[4] + sh[5] + sh[6] + sh[7];
  const float mu = s * (1.f / 768.f);
  const float var = s2 * (1.f / 768.f) - mu * mu;
  const float rstd = rsqrtf(var + 1e-6f);
  uint16_t* orow = out + row * 768;
  orow[t]       = f2bf((v0 - mu) * rstd * w[t] + b[t]);
  orow[t + 256] = f2bf((v1 - mu) * rstd * w[t + 256] + b[t + 256]);
  orow[t + 512] = f2bf((v2 - mu) * rstd * w[t + 512] + b[t + 512]);
}

// -------- batched transpose fp32 [R,Cc] -> bf16 [Cc,R] for all 4 weights ----
__global__ __launch_bounds__(256) void transpose_all(
    const float* __restrict__ w0, const float* __restrict__ w1,
    const float* __restrict__ w2, const float* __restrict__ w3,
    uint16_t* __restrict__ o0, uint16_t* __restrict__ o1,
    uint16_t* __restrict__ o2, uint16_t* __restrict__ o3) {
  int bid = blockIdx.x;
  const float* in;
  uint16_t* outp;
  int gx, ldin, ldout;
  if (bid < 1728) { in = w0; outp = o0; gx = 72; ldin = 2304; ldout = 768; }
  else if (bid < 2304) { bid -= 1728; in = w1; outp = o1; gx = 24; ldin = 768; ldout = 768; }
  else if (bid < 4608) { bid -= 2304; in = w2; outp = o2; gx = 96; ldin = 3072; ldout = 768; }
  else { bid -= 4608; in = w3; outp = o3; gx = 24; ldin = 768; ldout = 3072; }
  const int bx = bid % gx, by = bid / gx;

  __shared__ float tile[32][33];
  const int tx = threadIdx.x, ty = threadIdx.y;
  const size_t x = (size_t)bx * 32 + tx;
  const size_t y = (size_t)by * 32 + ty;
#pragma unroll
  for (int j = 0; j < 4; ++j) tile[ty + j * 8][tx] = in[(y + j * 8) * ldin + x];
  __syncthreads();
  const size_t x2 = (size_t)by * 32 + tx;
  const size_t y2 = (size_t)bx * 32 + ty;
#pragma unroll
  for (int j = 0; j < 4; ++j) outp[(y2 + j * 8) * ldout + x2] = f2bf(tile[tx][ty + j * 8]);
}

// -------- colsum of E, stage 1: 256 blocks -> partial[32][512] --------------
__global__ __launch_bounds__(256) void colsumP(const float* __restrict__ Ek,
                                               const float* __restrict__ Ev,
                                               float* __restrict__ partial) {
  const int b = blockIdx.x;
  const int kt = b & 7, nc = b >> 3;
  const float* src = (kt < 4) ? Ek : Ev;
  const int kbase = (kt & 3) * 64;
  const int kk = threadIdx.x & 63, s = threadIdx.x >> 6;
  float sum = 0.f;
#pragma unroll 4
  for (int i = 0; i < 64; ++i)
    sum += src[(size_t)(nc * 256 + s * 64 + i) * 256 + kbase + kk];
  __shared__ float red[4][64];
  red[s][kk] = sum;
  __syncthreads();
  if (s == 0) {
    const int cg = (kt >= 4 ? 256 : 0) + kbase + kk;
    partial[nc * 512 + cg] = (red[0][kk] + red[1][kk]) + (red[2][kk] + red[3][kk]);
  }
}

// -------- colsum stage 2: reduce 32 partials -> colsum[512] --------------
__global__ __launch_bounds__(256) void colsumR(const float* __restrict__ partial,
                                               float* __restrict__ colsum) {
  const int k = blockIdx.x * 256 + threadIdx.x;
  float s = 0.f;
#pragma unroll
  for (int nc = 0; nc < 32; ++nc) s += partial[nc * 512 + k];
  colsum[k] = s;
}

// ======== hkv gather TN: part[ns][b][k][c] = sum_{n in stripe} E[n,k] h[b][n,c]
__global__ __launch_bounds__(256) void hkv_tn(const float* __restrict__ Ek,
                                              const float* __restrict__ Ev,
                                              const uint16_t* __restrict__ h,
                                              float* __restrict__ part) {
  const int bid = blockIdx.x;
  const int wg = (bid & 7) * 96 + (bid >> 3);
  const int inner = wg & 31;
  const int kt = inner & 7, ns = inner >> 3;
  const int rest = wg >> 5;
  const int ct = rest % 12, b = rest / 12;
  const int k0 = kt * 64, c0 = ct * 64, nsb = ns * 2048;

  const float* Esrc = (k0 < 256) ? Ek : Ev;
  const int kc = k0 & 255;

  const int tid = threadIdx.x, wave = tid >> 6, lane = tid & 63;
  const int l16 = lane & 15, lhi = lane >> 4;
  const int wm = wave >> 1, wn = wave & 1;

  f32x4 acc[2][2];
#pragma unroll
  for (int m = 0; m < 2; ++m)
#pragma unroll
    for (int n = 0; n < 2; ++n) acc[m][n] = f32x4{0.f, 0.f, 0.f, 0.f};

  const int krow0 = kc + wm * 32 + l16;
  const uint16_t* Hb = h + ((size_t)b * 8192 + nsb + lhi * 8) * 768 + c0 + wn * 32 + l16;

  for (int n0 = 0; n0 < 2048; n0 += 32) {
    bf16x8 ef[2];
#pragma unroll
    for (int m = 0; m < 2; ++m) {
      const float* p = Esrc + (size_t)(nsb + n0 + lhi * 8) * 256 + krow0 + m * 16;
      union { bf16x8 v; uint16_t u[8]; } tu;
#pragma unroll
      for (int j = 0; j < 8; ++j) tu.u[j] = f2bf(p[(size_t)j * 256]);
      ef[m] = tu.v;
    }
    bf16x8 vf[2];
#pragma unroll
    for (int nf = 0; nf < 2; ++nf) {
      const uint16_t* p = Hb + (size_t)n0 * 768 + nf * 16;
      union { bf16x8 v; uint16_t u[8]; } tu;
#pragma unroll
      for (int j = 0; j < 8; ++j) tu.u[j] = p[(size_t)j * 768];
      vf[nf] = tu.v;
    }
#pragma unroll
    for (int m = 0; m < 2; ++m)
#pragma unroll
      for (int nf = 0; nf < 2; ++nf)
        acc[m][nf] = __builtin_amdgcn_mfma_f32_16x16x32_bf16(ef[m], vf[nf], acc[m][nf], 0, 0, 0);
  }

  float* outp = part + ((size_t)ns * 2 + b) * 393216;
#pragma unroll
  for (int m = 0; m < 2; ++m)
#pragma unroll
    for (int nf = 0; nf < 2; ++nf)
#pragma unroll
      for (int r = 0; r < 4; ++r)
        outp[(size_t)(k0 + wm * 32 + m * 16 + lhi * 4 + r) * 768 + c0 + wn * 32 + nf * 16 + l16] =
            acc[m][nf][r];
}

// -------- reduce 4 n-stripe fp32 partials -> bf16 hkv [b][512][768]
__global__ __launch_bounds__(256) void kv_reduce(const float* __restrict__ part,
                                                 uint16_t* __restrict__ hkv) {
  const int i = blockIdx.x * 256 + threadIdx.x;
  float s = part[i] + part[786432 + i] + part[2 * 786432 + i] + part[3 * 786432 + i];
  hkv[i] = f2bf(s);
}

// ---------------- small NT GEMM with z-batching (kvW step) ----------
template <int BM, int BN>
__global__ __launch_bounds__(256) void gemm_kvw(
    const uint16_t* __restrict__ Abase, const uint16_t* __restrict__ Bbase,
    uint16_t* __restrict__ Cbase, const float* __restrict__ bias,
    const float* __restrict__ rowscale, uint16_t* __restrict__ vpt,
    int Kd, int lda, int ldb, int ldc,
    int zdiv, size_t sAhi, size_t sAlo, size_t sBhi, size_t sBlo,
    size_t sChi, size_t sClo, int rs_z, int bias_z) {
  const int z = blockIdx.z;
  const int zhi = z / zdiv, zlo = z - zhi * zdiv;
  const uint16_t* A = Abase + zhi * sAhi + zlo * sAlo;
  const uint16_t* B = Bbase + zhi * sBhi + zlo * sBlo;
  const size_t coff = zhi * sChi + zlo * sClo;

  constexpr int WTM = BM / 2, WTN = BN / 2;
  constexpr int FM = WTM / 16, FN = WTN / 16;
  const int tid = threadIdx.x;
  const int wave = tid >> 6, lane = tid & 63;
  const int wm = wave >> 1, wn = wave & 1;
  const int l16 = lane & 15, lhi = lane >> 4;

  __shared__ __align__(16) uint16_t sA[BM * 32];
  __shared__ __align__(16) uint16_t sB[BN * 32];

  f32x4 acc[FM][FN];
#pragma unroll
  for (int m = 0; m < FM; ++m)
#pragma unroll
    for (int n = 0; n < FN; ++n) acc[m][n] = f32x4{0.f, 0.f, 0.f, 0.f};

  const int row0 = blockIdx.x * BM;
  const int col0 = blockIdx.y * BN;
  const int rr = tid >> 2, cq = tid & 3;

  for (int k0 = 0; k0 < Kd; k0 += 32) {
    __syncthreads();
#pragma unroll
    for (int is = 0; is < BM / 64; ++is) {
      const uint16_t* g = A + (size_t)(row0 + is * 64 + rr) * lda + k0 + cq * 8;
      gload16(g, &sA[is * 2048 + tid * 8]);
    }
#pragma unroll
    for (int is = 0; is < BN / 64; ++is) {
      const uint16_t* g = B + (size_t)(col0 + is * 64 + rr) * ldb + k0 + cq * 8;
      gload16(g, &sB[is * 2048 + tid * 8]);
    }
    __syncthreads();

    bf16x8 af[FM], bq[FN];
#pragma unroll
    for (int m = 0; m < FM; ++m)
      af[m] = *(const bf16x8*)(&sA[(wm * WTM + m * 16 + l16) * 32 + lhi * 8]);
#pragma unroll
    for (int n = 0; n < FN; ++n)
      bq[n] = *(const bf16x8*)(&sB[(wn * WTN + n * 16 + l16) * 32 + lhi * 8]);
#pragma unroll
    for (int m = 0; m < FM; ++m)
#pragma unroll
      for (int n = 0; n < FN; ++n)
        acc[m][n] = __builtin_amdgcn_mfma_f32_16x16x32_bf16(af[m], bq[n], acc[m][n], 0, 0, 0);
  }

#pragma unroll
  for (int m = 0; m < FM; ++m) {
#pragma unroll
    for (int n = 0; n < FN; ++n) {
      const int col = col0 + wn * WTN + n * 16 + l16;
      const float bv = bias[zlo * bias_z + col];
#pragma unroll
      for (int r = 0; r < 4; ++r) {
        const int row = row0 + wm * WTM + m * 16 + lhi * 4 + r;
        float v = acc[m][n][r] + rowscale[zlo * rs_z + row] * bv;
        if (zlo == 1) {
          vpt[(size_t)zhi * 196608 + (size_t)col * 256 + row] = f2bf(v);
        } else {
          Cbase[coff + (size_t)row * ldc + col] = f2bf(v);
        }
      }
    }
  }
}

// ======== fused attention: one (qtile64, b, h) block (verified) ========
__global__ __launch_bounds__(256, 3) void attn_fused(
    const uint16_t* __restrict__ q, const uint16_t* __restrict__ kproj,
    const uint16_t* __restrict__ vprojT, uint16_t* __restrict__ o) {
  const int bh = blockIdx.y;
  const int b = bh / 12, h = bh % 12;
  const int n0 = blockIdx.x * 64;
  const int tid = threadIdx.x, wave = tid >> 6, lane = tid & 63;
  const int l16 = lane & 15, lhi = lane >> 4;
  const int wm = wave >> 1, wn = wave & 1;

  __shared__ __align__(16) uint16_t sP[64 * 256];
  __shared__ float redm[2][64], reds[2][64], recs[64];

  const uint16_t* Kp = kproj + (size_t)b * 196608 + h * 64;
  const uint16_t* Qp = q + ((size_t)b * 8192 + n0) * 768 + h * 64;
  const uint16_t* Vp = vprojT + ((size_t)b * 768 + h * 64) * 256;

  f32x4 st[8][2];
#pragma unroll
  for (int m = 0; m < 8; ++m)
#pragma unroll
    for (int nf = 0; nf < 2; ++nf) st[m][nf] = f32x4{0.f, 0.f, 0.f, 0.f};
#pragma unroll
  for (int ks = 0; ks < 2; ++ks) {
    bf16x8 kf[8], qf[2];
#pragma unroll
    for (int m = 0; m < 8; ++m) {
      const int kvi = wm * 128 + m * 16 + l16;
      kf[m] = *(const bf16x8*)(Kp + (size_t)kvi * 768 + ks * 32 + lhi * 8);
    }
#pragma unroll
    for (int nf = 0; nf < 2; ++nf) {
      const int n = wn * 32 + nf * 16 + l16;
      qf[nf] = *(const bf16x8*)(Qp + (size_t)n * 768 + ks * 32 + lhi * 8);
    }
#pragma unroll
    for (int m = 0; m < 8; ++m)
#pragma unroll
      for (int nf = 0; nf < 2; ++nf)
        st[m][nf] = __builtin_amdgcn_mfma_f32_16x16x32_bf16(kf[m], qf[nf], st[m][nf], 0, 0, 0);
  }

  float pmax[2] = {-50.f, -50.f};
#pragma unroll
  for (int m = 0; m < 8; ++m)
#pragma unroll
    for (int nf = 0; nf < 2; ++nf)
#pragma unroll
      for (int r = 0; r < 4; ++r) {
        float v = fminf(fmaxf(st[m][nf][r] * 0.125f, -50.f), 50.f);
        st[m][nf][r] = v;
        pmax[nf] = fmaxf(pmax[nf], v);
      }
#pragma unroll
  for (int nf = 0; nf < 2; ++nf) {
    pmax[nf] = fmaxf(pmax[nf], __shfl_xor(pmax[nf], 16));
    pmax[nf] = fmaxf(pmax[nf], __shfl_xor(pmax[nf], 32));
  }
  if (lhi == 0) {
#pragma unroll
    for (int nf = 0; nf < 2; ++nf) redm[wm][wn * 32 + nf * 16 + l16] = pmax[nf];
  }
  __syncthreads();
  float M[2];
#pragma unroll
  for (int nf = 0; nf < 2; ++nf) {
    const int col = wn * 32 + nf * 16 + l16;
    M[nf] = fmaxf(redm[0][col], redm[1][col]);
  }

  float psum[2] = {0.f, 0.f};
#pragma unroll
  for (int m = 0; m < 8; ++m) {
#pragma unroll
    for (int nf = 0; nf < 2; ++nf) {
      float e0 = __expf(st[m][nf][0] - M[nf]);
      float e1 = __expf(st[m][nf][1] - M[nf]);
      float e2 = __expf(st[m][nf][2] - M[nf]);
      float e3 = __expf(st[m][nf][3] - M[nf]);
      psum[nf] += (e0 + e1) + (e2 + e3);
      uint2 pk;
      pk.x = (uint32_t)f2bf(e0) | ((uint32_t)f2bf(e1) << 16);
      pk.y = (uint32_t)f2bf(e2) | ((uint32_t)f2bf(e3) << 16);
      const int n = wn * 32 + nf * 16 + l16;
      const int kvb2 = (wm * 128 + m * 16 + lhi * 4) * 2;
      *(uint2*)((char*)sP + n * 512 + (kvb2 ^ ((n & 7) << 4))) = pk;
    }
  }
#pragma unroll
  for (int nf = 0; nf < 2; ++nf) {
    psum[nf] += __shfl_xor(psum[nf], 16);
    psum[nf] += __shfl_xor(psum[nf], 32);
  }
  if (lhi == 0) {
#pragma unroll
    for (int nf = 0; nf < 2; ++nf) reds[wm][wn * 32 + nf * 16 + l16] = psum[nf];
  }
  __syncthreads();
  if (wm == 0 && lhi == 0) {
#pragma unroll
    for (int nf = 0; nf < 2; ++nf) {
      const int col = wn * 32 + nf * 16 + l16;
      recs[col] = 1.f / (reds[0][col] + reds[1][col]);
    }
  }
  __syncthreads();

  f32x4 pacc[2][2];
#pragma unroll
  for (int mf = 0; mf < 2; ++mf)
#pragma unroll
    for (int nf = 0; nf < 2; ++nf) pacc[mf][nf] = f32x4{0.f, 0.f, 0.f, 0.f};
#pragma unroll
  for (int ks = 0; ks < 8; ++ks) {
    bf16x8 pa[2], vb[2];
#pragma unroll
    for (int mf = 0; mf < 2; ++mf) {
      const int n = wm * 32 + mf * 16 + l16;
      pa[mf] = *(const bf16x8*)((char*)sP + n * 512 + ((ks * 64 + lhi * 16) ^ ((n & 7) << 4)));
    }
#pragma unroll
    for (int nf = 0; nf < 2; ++nf) {
      const int d = wn * 32 + nf * 16 + l16;
      vb[nf] = *(const bf16x8*)(Vp + (size_t)d * 256 + ks * 32 + lhi * 8);
    }
#pragma unroll
    for (int mf = 0; mf < 2; ++mf)
#pragma unroll
      for (int nf = 0; nf < 2; ++nf)
        pacc[mf][nf] = __builtin_amdgcn_mfma_f32_16x16x32_bf16(pa[mf], vb[nf], pacc[mf][nf], 0, 0, 0);
  }
  uint16_t* orow = o + ((size_t)b * 8192 + n0) * 768 + h * 64;
#pragma unroll
  for (int mf = 0; mf < 2; ++mf) {
#pragma unroll
    for (int r = 0; r < 4; ++r) {
      const int n = wm * 32 + mf * 16 + lhi * 4 + r;
      const float inv = recs[n];
#pragma unroll
      for (int nf = 0; nf < 2; ++nf) {
        const int d = wn * 32 + nf * 16 + l16;
        orow[(size_t)n * 768 + d] = f2bf(pacc[mf][nf][r] * inv);
      }
    }
  }
}

// ======== gemm128: 128x128 NT, BK=32, 3 bufs (48 KB), 3 blocks/CU ========
template <bool OUTBF, bool HASBIAS, bool DOGELU, bool HASRES>
__global__ __launch_bounds__(256, 3) void gemm128(
    const uint16_t* __restrict__ A, const uint16_t* __restrict__ B,
    void* __restrict__ Cbase, const float* __restrict__ bias,
    const float* __restrict__ res, int Kd, int lda, int ldb, int ldc) {
  constexpr int PL = 4096;
  __shared__ __align__(16) uint16_t lds[3 * 2 * PL];

  const int nn = gridDim.y;
  const int nwg = gridDim.x * gridDim.y;
  const int bid = blockIdx.y * gridDim.x + blockIdx.x;
  const int q = nwg >> 3, r8 = nwg & 7, xcd = bid & 7, idx = bid >> 3;
  const int wg = (xcd < r8 ? xcd * (q + 1) : r8 * (q + 1) + (xcd - r8) * q) + idx;
  const int bm = wg / nn, bn = wg % nn;
  const int row0 = bm * 128, col0 = bn * 128;

  const int tid = threadIdx.x;
  const int wave = tid >> 6, lane = tid & 63;
  const int wm = wave >> 1, wn = wave & 1;
  const int l16 = lane & 15, lhi = lane >> 4;
  const int srow = tid >> 2, sq = tid & 3;

  auto stage = [&](int buf, int t) {
    const int k0 = t * 32;
    uint16_t* sa = lds + buf * 2 * PL;
#pragma unroll
    for (int j = 0; j < 2; ++j) {
      const int rw = j * 64 + srow;
      const int sl = sq ^ ((rw >> 1) & 3);
      gload16(A + (size_t)(row0 + rw) * lda + k0 + sl * 8, sa + rw * 32 + sq * 8);
    }
#pragma unroll
    for (int j = 0; j < 2; ++j) {
      const int rw = j * 64 + srow;
      const int sl = sq ^ ((rw >> 1) & 3);
      gload16(B + (size_t)(col0 + rw) * ldb + k0 + sl * 8, sa + PL + rw * 32 + sq * 8);
    }
  };

  f32x4 acc[4][4];
#pragma unroll
  for (int m = 0; m < 4; ++m)
#pragma unroll
    for (int n = 0; n < 4; ++n) acc[m][n] = f32x4{0.f, 0.f, 0.f, 0.f};

  const int NT = Kd >> 5;
  stage(0, 0);
  stage(1, 1);

  for (int t = 0; t < NT; ++t) {
    if (t < NT - 1) waitcnt_vm<4>();
    else waitcnt_vm<0>();
    __builtin_amdgcn_s_barrier();
    asm volatile("" ::: "memory");
    if (t + 2 < NT) stage((t + 2) % 3, t + 2);

    const uint16_t* sa = lds + (t % 3) * 2 * PL;
    const uint16_t* sb = sa + PL;
    bf16x8 af[4], bfv[4];
#pragma unroll
    for (int n = 0; n < 4; ++n) {
      const int rw = wn * 64 + n * 16 + l16;
      bfv[n] = *(const bf16x8*)(sb + rw * 32 + (lhi ^ ((rw >> 1) & 3)) * 8);
    }
#pragma unroll
    for (int m = 0; m < 4; ++m) {
      const int rw = wm * 64 + m * 16 + l16;
      af[m] = *(const bf16x8*)(sa + rw * 32 + (lhi ^ ((rw >> 1) & 3)) * 8);
    }
    __builtin_amdgcn_s_setprio(1);
#pragma unroll
    for (int m = 0; m < 4; ++m)
#pragma unroll
      for (int n = 0; n < 4; ++n)
        acc[m][n] = __builtin_amdgcn_mfma_f32_16x16x32_bf16(af[m], bfv[n], acc[m][n], 0, 0, 0);
    __builtin_amdgcn_s_setprio(0);
  }

  float* Cf = (float*)Cbase;
  uint16_t* Cb = (uint16_t*)Cbase;
#pragma unroll
  for (int m = 0; m < 4; ++m) {
#pragma unroll
    for (int n = 0; n < 4; ++n) {
      const int col = col0 + wn * 64 + n * 16 + l16;
      float bv = 0.f;
      if (HASBIAS) bv = bias[col];
#pragma unroll
      for (int r = 0; r < 4; ++r) {
        const int row = row0 + wm * 64 + m * 16 + lhi * 4 + r;
        float v = acc[m][n][r] + bv;
        if (DOGELU) v = gelu_f(v);
        const size_t cidx = (size_t)row * ldc + col;
        if (HASRES) v += res[cidx];
        if (OUTBF) Cb[cidx] = f2bf(v);
        else Cf[cidx] = v;
      }
    }
  }
}

// ======== gemm512: 256x128 NT, 512 thr / 8 waves (4x2), wave-tile 64x64,
// BK=32, 3 bufs (72 KB), 2 blocks/CU, counted vmcnt(3). ========
template <bool OUTBF, bool HASBIAS, bool DOGELU, bool HASRES>
__global__ __launch_bounds__(512, 4) void gemm512(
    const uint16_t* __restrict__ A, const uint16_t* __restrict__ B,
    void* __restrict__ Cbase, const float* __restrict__ bias,
    const float* __restrict__ res, int Kd, int lda, int ldb, int ldc) {
  constexpr int APL = 8192, BPL = 4096;
  __shared__ __align__(16) uint16_t lds[3 * (APL + BPL)];

  const int nn = gridDim.y;
  const int nwg = gridDim.x * gridDim.y;
  const int bid = blockIdx.y * gridDim.x + blockIdx.x;
  const int q = nwg >> 3, r8 = nwg & 7, xcd = bid & 7, idx = bid >> 3;
  const int wg = (xcd < r8 ? xcd * (q + 1) : r8 * (q + 1) + (xcd - r8) * q) + idx;
  const int bm = wg / nn, bn = wg % nn;
  const int row0 = bm * 256, col0 = bn * 128;

  const int tid = threadIdx.x;
  const int wave = tid >> 6, lane = tid & 63;
  const int wm = wave >> 1, wn = wave & 1;
  const int l16 = lane & 15, lhi = lane >> 4;
  const int srow = tid >> 2, sq = tid & 3;

  auto stage = [&](int buf, int t) {
    const int k0 = t * 32;
    uint16_t* sa = lds + buf * (APL + BPL);
#pragma unroll
    for (int j = 0; j < 2; ++j) {
      const int rw = j * 128 + srow;
      const int sl = sq ^ ((rw >> 1) & 3);
      gload16(A + (size_t)(row0 + rw) * lda + k0 + sl * 8, sa + rw * 32 + sq * 8);
    }
    {
      const int rw = srow;
      const int sl = sq ^ ((rw >> 1) & 3);
      gload16(B + (size_t)(col0 + rw) * ldb + k0 + sl * 8, sa + APL + rw * 32 + sq * 8);
    }
  };

  f32x4 acc[4][4];
#pragma unroll
  for (int m = 0; m < 4; ++m)
#pragma unroll
    for (int n = 0; n < 4; ++n) acc[m][n] = f32x4{0.f, 0.f, 0.f, 0.f};

  const int NT = Kd >> 5;
  stage(0, 0);
  stage(1, 1);

  for (int t = 0; t < NT; ++t) {
    if (t < NT - 1) waitcnt_vm<3>();
    else waitcnt_vm<0>();
    __builtin_amdgcn_s_barrier();
    asm volatile("" ::: "memory");
    if (t + 2 < NT) stage((t + 2) % 3, t + 2);

    const uint16_t* sa = lds + (t % 3) * (APL + BPL);
    const uint16_t* sb = sa + APL;
    bf16x8 af[4], bfv[4];
#pragma unroll
    for (int n = 0; n < 4; ++n) {
      const int rw = wn * 64 + n * 16 + l16;
      bfv[n] = *(const bf16x8*)(sb + rw * 32 + (lhi ^ ((rw >> 1) & 3)) * 8);
    }
#pragma unroll
    for (int m = 0; m < 4; ++m) {
      const int rw = wm * 64 + m * 16 + l16;
      af[m] = *(const bf16x8*)(sa + rw * 32 + (lhi ^ ((rw >> 1) & 3)) * 8);
    }
    __builtin_amdgcn_s_setprio(1);
#pragma unroll
    for (int m = 0; m < 4; ++m)
#pragma unroll
      for (int n = 0; n < 4; ++n)
        acc[m][n] = __builtin_amdgcn_mfma_f32_16x16x32_bf16(af[m], bfv[n], acc[m][n], 0, 0, 0);
    __builtin_amdgcn_s_setprio(0);
  }

  float* Cf = (float*)Cbase;
  uint16_t* Cb = (uint16_t*)Cbase;
#pragma unroll
  for (int m = 0; m < 4; ++m) {
#pragma unroll
    for (int n = 0; n < 4; ++n) {
      const int col = col0 + wn * 64 + n * 16 + l16;
      float bv = 0.f;
      if (HASBIAS) bv = bias[col];
#pragma unroll
      for (int r = 0; r < 4; ++r) {
        const int row = row0 + wm * 64 + m * 16 + lhi * 4 + r;
        float v = acc[m][n][r] + bv;
        if (DOGELU) v = gelu_f(v);
        const size_t cidx = (size_t)row * ldc + col;
        if (HASRES) v += res[cidx];
        if (OUTBF) Cb[cidx] = f2bf(v);
        else Cf[cidx] = v;
      }
    }
  }
}

extern "C" void kernel_launch(void* const* d_in, const int* in_sizes, int n_in,
                              void* d_out, int out_size, void* d_ws, size_t ws_size,
                              hipStream_t stream) {
  const float* x      = (const float*)d_in[0];
  const float* ln1_w  = (const float*)d_in[1];
  const float* ln1_b  = (const float*)d_in[2];
  const float* qkv_w  = (const float*)d_in[3];
  const float* qkv_b  = (const float*)d_in[4];
  const float* Ek     = (const float*)d_in[5];
  const float* Ev     = (const float*)d_in[6];
  const float* proj_w = (const float*)d_in[7];
  const float* proj_b = (const float*)d_in[8];
  const float* ln2_w  = (const float*)d_in[9];
  const float* ln2_b  = (const float*)d_in[10];
  const float* fc1_w  = (const float*)d_in[11];
  const float* fc1_b  = (const float*)d_in[12];
  const float* fc2_w  = (const float*)d_in[13];
  const float* fc2_b  = (const float*)d_in[14];
  float* out = (float*)d_out;

  char* w8 = (char*)d_ws;
  size_t off = 0;
  auto take = [&](size_t bytes) { char* p = w8 + off; off += bytes; return p; };
  uint16_t* qkv_wT  = (uint16_t*)take(2304ull * 768 * 2);
  uint16_t* proj_wT = (uint16_t*)take(768ull * 768 * 2);
  uint16_t* fc1_wT  = (uint16_t*)take(3072ull * 768 * 2);
  uint16_t* fc2_wT  = (uint16_t*)take(768ull * 3072 * 2);
  uint16_t* h_bf    = (uint16_t*)take(16384ull * 768 * 2);
  uint16_t* q_bf    = (uint16_t*)take(16384ull * 768 * 2);
  uint16_t* big     = (uint16_t*)take(100663296ull);           // hkv partials -> fc1 out
  uint16_t* hkv_bf  = (uint16_t*)take(2ull * 512 * 768 * 2);   // [b][512][768]
  uint16_t* kproj   = (uint16_t*)take(2ull * 256 * 768 * 2);   // [b][256][768] (k only)
  uint16_t* vprojT  = (uint16_t*)take(2ull * 768 * 256 * 2);   // [b][768][256]
  uint16_t* o_bf    = (uint16_t*)take(16384ull * 768 * 2);
  float* colsum     = (float*)take(512 * 4);
  float* cpartial   = (float*)take(32 * 512 * 4);
  float* part = (float*)big;  // [4][2][512][768] fp32 = 12.6 MB
  (void)ws_size; (void)in_sizes; (void)n_in; (void)out_size;

  // 1) all weight transposes in ONE launch; parallel colsum of E (2-stage)
  transpose_all<<<6912, dim3(32, 8), 0, stream>>>(
      qkv_w, proj_w, fc1_w, fc2_w, qkv_wT, proj_wT, fc1_wT, fc2_wT);
  colsumP<<<256, 256, 0, stream>>>(Ek, Ev, cpartial);
  colsumR<<<2, 256, 0, stream>>>(cpartial, colsum);
  // 2) LN1 -> h_bf
  ln768<<<16384, 256, 0, stream>>>(x, ln1_w, ln1_b, h_bf);
  // 3) q = h @ Wq + bq
  gemm128<true, true, false, false><<<dim3(128, 6), 256, 0, stream>>>(
      h_bf, qkv_wT, q_bf, qkv_b, nullptr, 768, 768, 768, 768);
  // 4) hkv = [Ek;Ev]^T @ h  (direct gather of fp32 E, 4 n-stripe partials)
  hkv_tn<<<768, 256, 0, stream>>>(Ek, Ev, h_bf, part);
  kv_reduce<<<3072, 256, 0, stream>>>(part, hkv_bf);
  // 5) k_proj = hkv_k @ Wk + colsumEk*bk -> kproj; v_proj transposed -> vprojT
  gemm_kvw<64, 64><<<dim3(4, 12, 4), 256, 0, stream>>>(
      hkv_bf, qkv_wT + 768ull * 768, kproj, qkv_b + 768, colsum, vprojT,
      768, 768, 768, 768,
      2, 512ull * 768, 256ull * 768, 0, 768ull * 768, 196608, 0, 256, 768);
  // 6) fused attention -> o_bf
  attn_fused<<<dim3(128, 24), 256, 0, stream>>>(q_bf, kproj, vprojT, o_bf);
  // 7) x2 = x + o @ proj_w + b -> d_out (fp32)
  gemm128<false, true, false, true><<<dim3(128, 6), 256, 0, stream>>>(
      o_bf, proj_wT, out, proj_b, x, 768, 768, 768, 768);
  // 8) LN2
  ln768<<<16384, 256, 0, stream>>>(out, ln2_w, ln2_b, h_bf);
  // 9) a1 = gelu(h2 @ fc1_w + b) -> big
  gemm512<true, true, true, false><<<dim3(64, 24), 512, 0, stream>>>(
      h_bf, fc1_wT, big, fc1_b, nullptr, 768, 768, 768, 3072);
  // 10) out = x2 + a1 @ fc2_w + b (in-place residual)
  gemm128<false, true, false, true><<<dim3(128, 6), 256, 0, stream>>>(
      big, fc2_wT, out, fc2_b, out, 3072, 3072, 3072, 768);
}

// Round 16
// 468.831 us; speedup vs baseline: 2.6889x; 1.0009x over previous
//
#include <hip/hip_runtime.h>
#include <cstdint>

#define DEV __device__ __forceinline__

typedef __bf16 bf16x8 __attribute__((ext_vector_type(8)));
typedef float f32x4 __attribute__((ext_vector_type(4)));

DEV uint16_t f2bf(float f) {
  uint32_t u = __float_as_uint(f);
  u += 0x7FFFu + ((u >> 16) & 1u);
  return (uint16_t)(u >> 16);
}
DEV float bf2f(uint16_t h) { return __uint_as_float(((uint32_t)h) << 16); }

DEV void gload16(const void* g, void* l) {
  __builtin_amdgcn_global_load_lds((const __attribute__((address_space(1))) void*)g,
                                   (__attribute__((address_space(3))) void*)l, 16, 0, 0);
}

template <int N> DEV void waitcnt_vm() {
  if constexpr (N == 0) asm volatile("s_waitcnt vmcnt(0)" ::: "memory");
  else if constexpr (N == 3) asm volatile("s_waitcnt vmcnt(3)" ::: "memory");
  else if constexpr (N == 4) asm volatile("s_waitcnt vmcnt(4)" ::: "memory");
  else static_assert(N == 0 || N == 3 || N == 4, "unsupported vmcnt");
}

// fast GELU (tanh form): max abs err vs erf-GELU ~3e-3
DEV float gelu_f(float v) {
  float u = v * (0.7978845608f + 0.0356774081f * v * v);
  return v / (1.f + __expf(-2.f * u));
}

// ---------------- LayerNorm over C=768, fp32 in -> bf16 out ----------------
// blocks >= 16384 (LN1 launch only) run colsumR tail: reduce cpartial -> colsum.
__global__ __launch_bounds__(256) void ln768(const float* __restrict__ x,
                                             const float* __restrict__ w,
                                             const float* __restrict__ b,
                                             uint16_t* __restrict__ out,
                                             const float* __restrict__ cpartial,
                                             float* __restrict__ colsum) {
  const int t = threadIdx.x;
  if (blockIdx.x >= 16384) {
    const int k = (blockIdx.x - 16384) * 256 + t;  // 0..511
    float s = 0.f;
#pragma unroll
    for (int nc = 0; nc < 32; ++nc) s += cpartial[nc * 512 + k];
    colsum[k] = s;
    return;
  }
  const size_t row = blockIdx.x;
  const float* xr = x + row * 768;
  float v0 = xr[t], v1 = xr[t + 256], v2 = xr[t + 512];
  float s = v0 + v1 + v2;
  float s2 = v0 * v0 + v1 * v1 + v2 * v2;
#pragma unroll
  for (int o = 32; o; o >>= 1) {
    s += __shfl_down(s, o);
    s2 += __shfl_down(s2, o);
  }
  __shared__ float sh[8];
  if ((t & 63) == 0) { sh[t >> 6] = s; sh[4 + (t >> 6)] = s2; }
  __syncthreads();
  s = sh[0] + sh[1] + sh[2] + sh[3];
  s2 = sh[4] + sh[5] + sh[6] + sh[7];
  const float mu = s * (1.f / 768.f);
  const float var = s2 * (1.f / 768.f) - mu * mu;
  const float rstd = rsqrtf(var + 1e-6f);
  uint16_t* orow = out + row * 768;
  orow[t]       = f2bf((v0 - mu) * rstd * w[t] + b[t]);
  orow[t + 256] = f2bf((v1 - mu) * rstd * w[t + 256] + b[t + 256]);
  orow[t + 512] = f2bf((v2 - mu) * rstd * w[t + 512] + b[t + 512]);
}

// -------- batched transpose fp32 [R,Cc] -> bf16 [Cc,R] for all 4 weights;
// blocks >= 6912 run colsumP tail (E column-sum partials, 256 blocks). -------
__global__ __launch_bounds__(256) void transpose_all(
    const float* __restrict__ w0, const float* __restrict__ w1,
    const float* __restrict__ w2, const float* __restrict__ w3,
    uint16_t* __restrict__ o0, uint16_t* __restrict__ o1,
    uint16_t* __restrict__ o2, uint16_t* __restrict__ o3,
    const float* __restrict__ Ek, const float* __restrict__ Ev,
    float* __restrict__ cpartial) {
  int bid = blockIdx.x;
  const int tid = threadIdx.y * 32 + threadIdx.x;
  if (bid >= 6912) {
    // colsumP: block b sums a 256-row chunk of one 64-col group of Ek/Ev
    const int b = bid - 6912;  // 0..255
    const int kt = b & 7, nc = b >> 3;
    const float* src = (kt < 4) ? Ek : Ev;
    const int kbase = (kt & 3) * 64;
    const int kk = tid & 63, s = tid >> 6;
    float sum = 0.f;
#pragma unroll 4
    for (int i = 0; i < 64; ++i)
      sum += src[(size_t)(nc * 256 + s * 64 + i) * 256 + kbase + kk];
    __shared__ float red[4][64];
    red[s][kk] = sum;
    __syncthreads();
    if (s == 0) {
      const int cg = (kt >= 4 ? 256 : 0) + kbase + kk;
      cpartial[nc * 512 + cg] = (red[0][kk] + red[1][kk]) + (red[2][kk] + red[3][kk]);
    }
    return;
  }
  const float* in;
  uint16_t* outp;
  int gx, ldin, ldout;
  if (bid < 1728) { in = w0; outp = o0; gx = 72; ldin = 2304; ldout = 768; }
  else if (bid < 2304) { bid -= 1728; in = w1; outp = o1; gx = 24; ldin = 768; ldout = 768; }
  else if (bid < 4608) { bid -= 2304; in = w2; outp = o2; gx = 96; ldin = 3072; ldout = 768; }
  else { bid -= 4608; in = w3; outp = o3; gx = 24; ldin = 768; ldout = 3072; }
  const int bx = bid % gx, by = bid / gx;

  __shared__ float tile[32][33];
  const int tx = threadIdx.x, ty = threadIdx.y;
  const size_t x = (size_t)bx * 32 + tx;
  const size_t y = (size_t)by * 32 + ty;
#pragma unroll
  for (int j = 0; j < 4; ++j) tile[ty + j * 8][tx] = in[(y + j * 8) * ldin + x];
  __syncthreads();
  const size_t x2 = (size_t)by * 32 + tx;
  const size_t y2 = (size_t)bx * 32 + ty;
#pragma unroll
  for (int j = 0; j < 4; ++j) outp[(y2 + j * 8) * ldout + x2] = f2bf(tile[tx][ty + j * 8]);
}

// ======== hkv gather TN: part[ns][b][k][c] = sum_{n in stripe} E[n,k] h[b][n,c]
__global__ __launch_bounds__(256) void hkv_tn(const float* __restrict__ Ek,
                                              const float* __restrict__ Ev,
                                              const uint16_t* __restrict__ h,
                                              float* __restrict__ part) {
  const int bid = blockIdx.x;
  const int wg = (bid & 7) * 96 + (bid >> 3);
  const int inner = wg & 31;
  const int kt = inner & 7, ns = inner >> 3;
  const int rest = wg >> 5;
  const int ct = rest % 12, b = rest / 12;
  const int k0 = kt * 64, c0 = ct * 64, nsb = ns * 2048;

  const float* Esrc = (k0 < 256) ? Ek : Ev;
  const int kc = k0 & 255;

  const int tid = threadIdx.x, wave = tid >> 6, lane = tid & 63;
  const int l16 = lane & 15, lhi = lane >> 4;
  const int wm = wave >> 1, wn = wave & 1;

  f32x4 acc[2][2];
#pragma unroll
  for (int m = 0; m < 2; ++m)
#pragma unroll
    for (int n = 0; n < 2; ++n) acc[m][n] = f32x4{0.f, 0.f, 0.f, 0.f};

  const int krow0 = kc + wm * 32 + l16;
  const uint16_t* Hb = h + ((size_t)b * 8192 + nsb + lhi * 8) * 768 + c0 + wn * 32 + l16;

  for (int n0 = 0; n0 < 2048; n0 += 32) {
    bf16x8 ef[2];
#pragma unroll
    for (int m = 0; m < 2; ++m) {
      const float* p = Esrc + (size_t)(nsb + n0 + lhi * 8) * 256 + krow0 + m * 16;
      union { bf16x8 v; uint16_t u[8]; } tu;
#pragma unroll
      for (int j = 0; j < 8; ++j) tu.u[j] = f2bf(p[(size_t)j * 256]);
      ef[m] = tu.v;
    }
    bf16x8 vf[2];
#pragma unroll
    for (int nf = 0; nf < 2; ++nf) {
      const uint16_t* p = Hb + (size_t)n0 * 768 + nf * 16;
      union { bf16x8 v; uint16_t u[8]; } tu;
#pragma unroll
      for (int j = 0; j < 8; ++j) tu.u[j] = p[(size_t)j * 768];
      vf[nf] = tu.v;
    }
#pragma unroll
    for (int m = 0; m < 2; ++m)
#pragma unroll
      for (int nf = 0; nf < 2; ++nf)
        acc[m][nf] = __builtin_amdgcn_mfma_f32_16x16x32_bf16(ef[m], vf[nf], acc[m][nf], 0, 0, 0);
  }

  float* outp = part + ((size_t)ns * 2 + b) * 393216;
#pragma unroll
  for (int m = 0; m < 2; ++m)
#pragma unroll
    for (int nf = 0; nf < 2; ++nf)
#pragma unroll
      for (int r = 0; r < 4; ++r)
        outp[(size_t)(k0 + wm * 32 + m * 16 + lhi * 4 + r) * 768 + c0 + wn * 32 + nf * 16 + l16] =
            acc[m][nf][r];
}

// -------- reduce 4 n-stripe fp32 partials -> bf16 hkv [b][512][768]
__global__ __launch_bounds__(256) void kv_reduce(const float* __restrict__ part,
                                                 uint16_t* __restrict__ hkv) {
  const int i = blockIdx.x * 256 + threadIdx.x;
  float s = part[i] + part[786432 + i] + part[2 * 786432 + i] + part[3 * 786432 + i];
  hkv[i] = f2bf(s);
}

// ---------------- small NT GEMM with z-batching (kvW step) ----------
template <int BM, int BN>
__global__ __launch_bounds__(256) void gemm_kvw(
    const uint16_t* __restrict__ Abase, const uint16_t* __restrict__ Bbase,
    uint16_t* __restrict__ Cbase, const float* __restrict__ bias,
    const float* __restrict__ rowscale, uint16_t* __restrict__ vpt,
    int Kd, int lda, int ldb, int ldc,
    int zdiv, size_t sAhi, size_t sAlo, size_t sBhi, size_t sBlo,
    size_t sChi, size_t sClo, int rs_z, int bias_z) {
  const int z = blockIdx.z;
  const int zhi = z / zdiv, zlo = z - zhi * zdiv;
  const uint16_t* A = Abase + zhi * sAhi + zlo * sAlo;
  const uint16_t* B = Bbase + zhi * sBhi + zlo * sBlo;
  const size_t coff = zhi * sChi + zlo * sClo;

  constexpr int WTM = BM / 2, WTN = BN / 2;
  constexpr int FM = WTM / 16, FN = WTN / 16;
  const int tid = threadIdx.x;
  const int wave = tid >> 6, lane = tid & 63;
  const int wm = wave >> 1, wn = wave & 1;
  const int l16 = lane & 15, lhi = lane >> 4;

  __shared__ __align__(16) uint16_t sA[BM * 32];
  __shared__ __align__(16) uint16_t sB[BN * 32];

  f32x4 acc[FM][FN];
#pragma unroll
  for (int m = 0; m < FM; ++m)
#pragma unroll
    for (int n = 0; n < FN; ++n) acc[m][n] = f32x4{0.f, 0.f, 0.f, 0.f};

  const int row0 = blockIdx.x * BM;
  const int col0 = blockIdx.y * BN;
  const int rr = tid >> 2, cq = tid & 3;

  for (int k0 = 0; k0 < Kd; k0 += 32) {
    __syncthreads();
#pragma unroll
    for (int is = 0; is < BM / 64; ++is) {
      const uint16_t* g = A + (size_t)(row0 + is * 64 + rr) * lda + k0 + cq * 8;
      gload16(g, &sA[is * 2048 + tid * 8]);
    }
#pragma unroll
    for (int is = 0; is < BN / 64; ++is) {
      const uint16_t* g = B + (size_t)(col0 + is * 64 + rr) * ldb + k0 + cq * 8;
      gload16(g, &sB[is * 2048 + tid * 8]);
    }
    __syncthreads();

    bf16x8 af[FM], bq[FN];
#pragma unroll
    for (int m = 0; m < FM; ++m)
      af[m] = *(const bf16x8*)(&sA[(wm * WTM + m * 16 + l16) * 32 + lhi * 8]);
#pragma unroll
    for (int n = 0; n < FN; ++n)
      bq[n] = *(const bf16x8*)(&sB[(wn * WTN + n * 16 + l16) * 32 + lhi * 8]);
#pragma unroll
    for (int m = 0; m < FM; ++m)
#pragma unroll
      for (int n = 0; n < FN; ++n)
        acc[m][n] = __builtin_amdgcn_mfma_f32_16x16x32_bf16(af[m], bq[n], acc[m][n], 0, 0, 0);
  }

#pragma unroll
  for (int m = 0; m < FM; ++m) {
#pragma unroll
    for (int n = 0; n < FN; ++n) {
      const int col = col0 + wn * WTN + n * 16 + l16;
      const float bv = bias[zlo * bias_z + col];
#pragma unroll
      for (int r = 0; r < 4; ++r) {
        const int row = row0 + wm * WTM + m * 16 + lhi * 4 + r;
        float v = acc[m][n][r] + rowscale[zlo * rs_z + row] * bv;
        if (zlo == 1) {
          vpt[(size_t)zhi * 196608 + (size_t)col * 256 + row] = f2bf(v);
        } else {
          Cbase[coff + (size_t)row * ldc + col] = f2bf(v);
        }
      }
    }
  }
}

// ======== fused attention: one (qtile64, b, h) block (verified) ========
__global__ __launch_bounds__(256, 3) void attn_fused(
    const uint16_t* __restrict__ q, const uint16_t* __restrict__ kproj,
    const uint16_t* __restrict__ vprojT, uint16_t* __restrict__ o) {
  const int bh = blockIdx.y;
  const int b = bh / 12, h = bh % 12;
  const int n0 = blockIdx.x * 64;
  const int tid = threadIdx.x, wave = tid >> 6, lane = tid & 63;
  const int l16 = lane & 15, lhi = lane >> 4;
  const int wm = wave >> 1, wn = wave & 1;

  __shared__ __align__(16) uint16_t sP[64 * 256];
  __shared__ float redm[2][64], reds[2][64], recs[64];

  const uint16_t* Kp = kproj + (size_t)b * 196608 + h * 64;
  const uint16_t* Qp = q + ((size_t)b * 8192 + n0) * 768 + h * 64;
  const uint16_t* Vp = vprojT + ((size_t)b * 768 + h * 64) * 256;

  f32x4 st[8][2];
#pragma unroll
  for (int m = 0; m < 8; ++m)
#pragma unroll
    for (int nf = 0; nf < 2; ++nf) st[m][nf] = f32x4{0.f, 0.f, 0.f, 0.f};
#pragma unroll
  for (int ks = 0; ks < 2; ++ks) {
    bf16x8 kf[8], qf[2];
#pragma unroll
    for (int m = 0; m < 8; ++m) {
      const int kvi = wm * 128 + m * 16 + l16;
      kf[m] = *(const bf16x8*)(Kp + (size_t)kvi * 768 + ks * 32 + lhi * 8);
    }
#pragma unroll
    for (int nf = 0; nf < 2; ++nf) {
      const int n = wn * 32 + nf * 16 + l16;
      qf[nf] = *(const bf16x8*)(Qp + (size_t)n * 768 + ks * 32 + lhi * 8);
    }
#pragma unroll
    for (int m = 0; m < 8; ++m)
#pragma unroll
      for (int nf = 0; nf < 2; ++nf)
        st[m][nf] = __builtin_amdgcn_mfma_f32_16x16x32_bf16(kf[m], qf[nf], st[m][nf], 0, 0, 0);
  }

  float pmax[2] = {-50.f, -50.f};
#pragma unroll
  for (int m = 0; m < 8; ++m)
#pragma unroll
    for (int nf = 0; nf < 2; ++nf)
#pragma unroll
      for (int r = 0; r < 4; ++r) {
        float v = fminf(fmaxf(st[m][nf][r] * 0.125f, -50.f), 50.f);
        st[m][nf][r] = v;
        pmax[nf] = fmaxf(pmax[nf], v);
      }
#pragma unroll
  for (int nf = 0; nf < 2; ++nf) {
    pmax[nf] = fmaxf(pmax[nf], __shfl_xor(pmax[nf], 16));
    pmax[nf] = fmaxf(pmax[nf], __shfl_xor(pmax[nf], 32));
  }
  if (lhi == 0) {
#pragma unroll
    for (int nf = 0; nf < 2; ++nf) redm[wm][wn * 32 + nf * 16 + l16] = pmax[nf];
  }
  __syncthreads();
  float M[2];
#pragma unroll
  for (int nf = 0; nf < 2; ++nf) {
    const int col = wn * 32 + nf * 16 + l16;
    M[nf] = fmaxf(redm[0][col], redm[1][col]);
  }

  float psum[2] = {0.f, 0.f};
#pragma unroll
  for (int m = 0; m < 8; ++m) {
#pragma unroll
    for (int nf = 0; nf < 2; ++nf) {
      float e0 = __expf(st[m][nf][0] - M[nf]);
      float e1 = __expf(st[m][nf][1] - M[nf]);
      float e2 = __expf(st[m][nf][2] - M[nf]);
      float e3 = __expf(st[m][nf][3] - M[nf]);
      psum[nf] += (e0 + e1) + (e2 + e3);
      uint2 pk;
      pk.x = (uint32_t)f2bf(e0) | ((uint32_t)f2bf(e1) << 16);
      pk.y = (uint32_t)f2bf(e2) | ((uint32_t)f2bf(e3) << 16);
      const int n = wn * 32 + nf * 16 + l16;
      const int kvb2 = (wm * 128 + m * 16 + lhi * 4) * 2;
      *(uint2*)((char*)sP + n * 512 + (kvb2 ^ ((n & 7) << 4))) = pk;
    }
  }
#pragma unroll
  for (int nf = 0; nf < 2; ++nf) {
    psum[nf] += __shfl_xor(psum[nf], 16);
    psum[nf] += __shfl_xor(psum[nf], 32);
  }
  if (lhi == 0) {
#pragma unroll
    for (int nf = 0; nf < 2; ++nf) reds[wm][wn * 32 + nf * 16 + l16] = psum[nf];
  }
  __syncthreads();
  if (wm == 0 && lhi == 0) {
#pragma unroll
    for (int nf = 0; nf < 2; ++nf) {
      const int col = wn * 32 + nf * 16 + l16;
      recs[col] = 1.f / (reds[0][col] + reds[1][col]);
    }
  }
  __syncthreads();

  f32x4 pacc[2][2];
#pragma unroll
  for (int mf = 0; mf < 2; ++mf)
#pragma unroll
    for (int nf = 0; nf < 2; ++nf) pacc[mf][nf] = f32x4{0.f, 0.f, 0.f, 0.f};
#pragma unroll
  for (int ks = 0; ks < 8; ++ks) {
    bf16x8 pa[2], vb[2];
#pragma unroll
    for (int mf = 0; mf < 2; ++mf) {
      const int n = wm * 32 + mf * 16 + l16;
      pa[mf] = *(const bf16x8*)((char*)sP + n * 512 + ((ks * 64 + lhi * 16) ^ ((n & 7) << 4)));
    }
#pragma unroll
    for (int nf = 0; nf < 2; ++nf) {
      const int d = wn * 32 + nf * 16 + l16;
      vb[nf] = *(const bf16x8*)(Vp + (size_t)d * 256 + ks * 32 + lhi * 8);
    }
#pragma unroll
    for (int mf = 0; mf < 2; ++mf)
#pragma unroll
      for (int nf = 0; nf < 2; ++nf)
        pacc[mf][nf] = __builtin_amdgcn_mfma_f32_16x16x32_bf16(pa[mf], vb[nf], pacc[mf][nf], 0, 0, 0);
  }
  uint16_t* orow = o + ((size_t)b * 8192 + n0) * 768 + h * 64;
#pragma unroll
  for (int mf = 0; mf < 2; ++mf) {
#pragma unroll
    for (int r = 0; r < 4; ++r) {
      const int n = wm * 32 + mf * 16 + lhi * 4 + r;
      const float inv = recs[n];
#pragma unroll
      for (int nf = 0; nf < 2; ++nf) {
        const int d = wn * 32 + nf * 16 + l16;
        orow[(size_t)n * 768 + d] = f2bf(pacc[mf][nf][r] * inv);
      }
    }
  }
}

// ======== gemm128: 128x128 NT, BK=32, 3 bufs (48 KB), 3 blocks/CU ========
template <bool OUTBF, bool HASBIAS, bool DOGELU, bool HASRES>
__global__ __launch_bounds__(256, 3) void gemm128(
    const uint16_t* __restrict__ A, const uint16_t* __restrict__ B,
    void* __restrict__ Cbase, const float* __restrict__ bias,
    const float* __restrict__ res, int Kd, int lda, int ldb, int ldc) {
  constexpr int PL = 4096;
  __shared__ __align__(16) uint16_t lds[3 * 2 * PL];

  const int nn = gridDim.y;
  const int nwg = gridDim.x * gridDim.y;
  const int bid = blockIdx.y * gridDim.x + blockIdx.x;
  const int q = nwg >> 3, r8 = nwg & 7, xcd = bid & 7, idx = bid >> 3;
  const int wg = (xcd < r8 ? xcd * (q + 1) : r8 * (q + 1) + (xcd - r8) * q) + idx;
  const int bm = wg / nn, bn = wg % nn;
  const int row0 = bm * 128, col0 = bn * 128;

  const int tid = threadIdx.x;
  const int wave = tid >> 6, lane = tid & 63;
  const int wm = wave >> 1, wn = wave & 1;
  const int l16 = lane & 15, lhi = lane >> 4;
  const int srow = tid >> 2, sq = tid & 3;

  auto stage = [&](int buf, int t) {
    const int k0 = t * 32;
    uint16_t* sa = lds + buf * 2 * PL;
#pragma unroll
    for (int j = 0; j < 2; ++j) {
      const int rw = j * 64 + srow;
      const int sl = sq ^ ((rw >> 1) & 3);
      gload16(A + (size_t)(row0 + rw) * lda + k0 + sl * 8, sa + rw * 32 + sq * 8);
    }
#pragma unroll
    for (int j = 0; j < 2; ++j) {
      const int rw = j * 64 + srow;
      const int sl = sq ^ ((rw >> 1) & 3);
      gload16(B + (size_t)(col0 + rw) * ldb + k0 + sl * 8, sa + PL + rw * 32 + sq * 8);
    }
  };

  f32x4 acc[4][4];
#pragma unroll
  for (int m = 0; m < 4; ++m)
#pragma unroll
    for (int n = 0; n < 4; ++n) acc[m][n] = f32x4{0.f, 0.f, 0.f, 0.f};

  const int NT = Kd >> 5;
  stage(0, 0);
  stage(1, 1);

  for (int t = 0; t < NT; ++t) {
    if (t < NT - 1) waitcnt_vm<4>();
    else waitcnt_vm<0>();
    __builtin_amdgcn_s_barrier();
    asm volatile("" ::: "memory");
    if (t + 2 < NT) stage((t + 2) % 3, t + 2);

    const uint16_t* sa = lds + (t % 3) * 2 * PL;
    const uint16_t* sb = sa + PL;
    bf16x8 af[4], bfv[4];
#pragma unroll
    for (int n = 0; n < 4; ++n) {
      const int rw = wn * 64 + n * 16 + l16;
      bfv[n] = *(const bf16x8*)(sb + rw * 32 + (lhi ^ ((rw >> 1) & 3)) * 8);
    }
#pragma unroll
    for (int m = 0; m < 4; ++m) {
      const int rw = wm * 64 + m * 16 + l16;
      af[m] = *(const bf16x8*)(sa + rw * 32 + (lhi ^ ((rw >> 1) & 3)) * 8);
    }
    __builtin_amdgcn_s_setprio(1);
#pragma unroll
    for (int m = 0; m < 4; ++m)
#pragma unroll
      for (int n = 0; n < 4; ++n)
        acc[m][n] = __builtin_amdgcn_mfma_f32_16x16x32_bf16(af[m], bfv[n], acc[m][n], 0, 0, 0);
    __builtin_amdgcn_s_setprio(0);
  }

  float* Cf = (float*)Cbase;
  uint16_t* Cb = (uint16_t*)Cbase;
#pragma unroll
  for (int m = 0; m < 4; ++m) {
#pragma unroll
    for (int n = 0; n < 4; ++n) {
      const int col = col0 + wn * 64 + n * 16 + l16;
      float bv = 0.f;
      if (HASBIAS) bv = bias[col];
#pragma unroll
      for (int r = 0; r < 4; ++r) {
        const int row = row0 + wm * 64 + m * 16 + lhi * 4 + r;
        float v = acc[m][n][r] + bv;
        if (DOGELU) v = gelu_f(v);
        const size_t cidx = (size_t)row * ldc + col;
        if (HASRES) v += res[cidx];
        if (OUTBF) Cb[cidx] = f2bf(v);
        else Cf[cidx] = v;
      }
    }
  }
}

// ======== gemm512: 256x128 NT, 512 thr / 8 waves (4x2), wave-tile 64x64,
// BK=32, 3 bufs (72 KB), 2 blocks/CU, counted vmcnt(3). ========
template <bool OUTBF, bool HASBIAS, bool DOGELU, bool HASRES>
__global__ __launch_bounds__(512, 4) void gemm512(
    const uint16_t* __restrict__ A, const uint16_t* __restrict__ B,
    void* __restrict__ Cbase, const float* __restrict__ bias,
    const float* __restrict__ res, int Kd, int lda, int ldb, int ldc) {
  constexpr int APL = 8192, BPL = 4096;
  __shared__ __align__(16) uint16_t lds[3 * (APL + BPL)];

  const int nn = gridDim.y;
  const int nwg = gridDim.x * gridDim.y;
  const int bid = blockIdx.y * gridDim.x + blockIdx.x;
  const int q = nwg >> 3, r8 = nwg & 7, xcd = bid & 7, idx = bid >> 3;
  const int wg = (xcd < r8 ? xcd * (q + 1) : r8 * (q + 1) + (xcd - r8) * q) + idx;
  const int bm = wg / nn, bn = wg % nn;
  const int row0 = bm * 256, col0 = bn * 128;

  const int tid = threadIdx.x;
  const int wave = tid >> 6, lane = tid & 63;
  const int wm = wave >> 1, wn = wave & 1;
  const int l16 = lane & 15, lhi = lane >> 4;
  const int srow = tid >> 2, sq = tid & 3;

  auto stage = [&](int buf, int t) {
    const int k0 = t * 32;
    uint16_t* sa = lds + buf * (APL + BPL);
#pragma unroll
    for (int j = 0; j < 2; ++j) {
      const int rw = j * 128 + srow;
      const int sl = sq ^ ((rw >> 1) & 3);
      gload16(A + (size_t)(row0 + rw) * lda + k0 + sl * 8, sa + rw * 32 + sq * 8);
    }
    {
      const int rw = srow;
      const int sl = sq ^ ((rw >> 1) & 3);
      gload16(B + (size_t)(col0 + rw) * ldb + k0 + sl * 8, sa + APL + rw * 32 + sq * 8);
    }
  };

  f32x4 acc[4][4];
#pragma unroll
  for (int m = 0; m < 4; ++m)
#pragma unroll
    for (int n = 0; n < 4; ++n) acc[m][n] = f32x4{0.f, 0.f, 0.f, 0.f};

  const int NT = Kd >> 5;
  stage(0, 0);
  stage(1, 1);

  for (int t = 0; t < NT; ++t) {
    if (t < NT - 1) waitcnt_vm<3>();
    else waitcnt_vm<0>();
    __builtin_amdgcn_s_barrier();
    asm volatile("" ::: "memory");
    if (t + 2 < NT) stage((t + 2) % 3, t + 2);

    const uint16_t* sa = lds + (t % 3) * (APL + BPL);
    const uint16_t* sb = sa + APL;
    bf16x8 af[4], bfv[4];
#pragma unroll
    for (int n = 0; n < 4; ++n) {
      const int rw = wn * 64 + n * 16 + l16;
      bfv[n] = *(const bf16x8*)(sb + rw * 32 + (lhi ^ ((rw >> 1) & 3)) * 8);
    }
#pragma unroll
    for (int m = 0; m < 4; ++m) {
      const int rw = wm * 64 + m * 16 + l16;
      af[m] = *(const bf16x8*)(sa + rw * 32 + (lhi ^ ((rw >> 1) & 3)) * 8);
    }
    __builtin_amdgcn_s_setprio(1);
#pragma unroll
    for (int m = 0; m < 4; ++m)
#pragma unroll
      for (int n = 0; n < 4; ++n)
        acc[m][n] = __builtin_amdgcn_mfma_f32_16x16x32_bf16(af[m], bfv[n], acc[m][n], 0, 0, 0);
    __builtin_amdgcn_s_setprio(0);
  }

  float* Cf = (float*)Cbase;
  uint16_t* Cb = (uint16_t*)Cbase;
#pragma unroll
  for (int m = 0; m < 4; ++m) {
#pragma unroll
    for (int n = 0; n < 4; ++n) {
      const int col = col0 + wn * 64 + n * 16 + l16;
      float bv = 0.f;
      if (HASBIAS) bv = bias[col];
#pragma unroll
      for (int r = 0; r < 4; ++r) {
        const int row = row0 + wm * 64 + m * 16 + lhi * 4 + r;
        float v = acc[m][n][r] + bv;
        if (DOGELU) v = gelu_f(v);
        const size_t cidx = (size_t)row * ldc + col;
        if (HASRES) v += res[cidx];
        if (OUTBF) Cb[cidx] = f2bf(v);
        else Cf[cidx] = v;
      }
    }
  }
}

extern "C" void kernel_launch(void* const* d_in, const int* in_sizes, int n_in,
                              void* d_out, int out_size, void* d_ws, size_t ws_size,
                              hipStream_t stream) {
  const float* x      = (const float*)d_in[0];
  const float* ln1_w  = (const float*)d_in[1];
  const float* ln1_b  = (const float*)d_in[2];
  const float* qkv_w  = (const float*)d_in[3];
  const float* qkv_b  = (const float*)d_in[4];
  const float* Ek     = (const float*)d_in[5];
  const float* Ev     = (const float*)d_in[6];
  const float* proj_w = (const float*)d_in[7];
  const float* proj_b = (const float*)d_in[8];
  const float* ln2_w  = (const float*)d_in[9];
  const float* ln2_b  = (const float*)d_in[10];
  const float* fc1_w  = (const float*)d_in[11];
  const float* fc1_b  = (const float*)d_in[12];
  const float* fc2_w  = (const float*)d_in[13];
  const float* fc2_b  = (const float*)d_in[14];
  float* out = (float*)d_out;

  char* w8 = (char*)d_ws;
  size_t off = 0;
  auto take = [&](size_t bytes) { char* p = w8 + off; off += bytes; return p; };
  uint16_t* qkv_wT  = (uint16_t*)take(2304ull * 768 * 2);
  uint16_t* proj_wT = (uint16_t*)take(768ull * 768 * 2);
  uint16_t* fc1_wT  = (uint16_t*)take(3072ull * 768 * 2);
  uint16_t* fc2_wT  = (uint16_t*)take(768ull * 3072 * 2);
  uint16_t* h_bf    = (uint16_t*)take(16384ull * 768 * 2);
  uint16_t* q_bf    = (uint16_t*)take(16384ull * 768 * 2);
  uint16_t* big     = (uint16_t*)take(100663296ull);           // hkv partials -> fc1 out
  uint16_t* hkv_bf  = (uint16_t*)take(2ull * 512 * 768 * 2);   // [b][512][768]
  uint16_t* kproj   = (uint16_t*)take(2ull * 256 * 768 * 2);   // [b][256][768] (k only)
  uint16_t* vprojT  = (uint16_t*)take(2ull * 768 * 256 * 2);   // [b][768][256]
  uint16_t* o_bf    = (uint16_t*)take(16384ull * 768 * 2);
  float* colsum     = (float*)take(512 * 4);
  float* cpartial   = (float*)take(32 * 512 * 4);
  float* part = (float*)big;  // [4][2][512][768] fp32 = 12.6 MB
  (void)ws_size; (void)in_sizes; (void)n_in; (void)out_size;

  // 1) weight transposes + colsumP (E column-sum partials) in ONE launch
  transpose_all<<<7168, dim3(32, 8), 0, stream>>>(
      qkv_w, proj_w, fc1_w, fc2_w, qkv_wT, proj_wT, fc1_wT, fc2_wT,
      Ek, Ev, cpartial);
  // 2) LN1 -> h_bf  (+2 tail blocks: colsumR reduces cpartial -> colsum)
  ln768<<<16386, 256, 0, stream>>>(x, ln1_w, ln1_b, h_bf, cpartial, colsum);
  // 3) q = h @ Wq + bq
  gemm128<true, true, false, false><<<dim3(128, 6), 256, 0, stream>>>(
      h_bf, qkv_wT, q_bf, qkv_b, nullptr, 768, 768, 768, 768);
  // 4) hkv = [Ek;Ev]^T @ h  (direct gather of fp32 E, 4 n-stripe partials)
  hkv_tn<<<768, 256, 0, stream>>>(Ek, Ev, h_bf, part);
  kv_reduce<<<3072, 256, 0, stream>>>(part, hkv_bf);
  // 5) k_proj = hkv_k @ Wk + colsumEk*bk -> kproj; v_proj transposed -> vprojT
  gemm_kvw<64, 64><<<dim3(4, 12, 4), 256, 0, stream>>>(
      hkv_bf, qkv_wT + 768ull * 768, kproj, qkv_b + 768, colsum, vprojT,
      768, 768, 768, 768,
      2, 512ull * 768, 256ull * 768, 0, 768ull * 768, 196608, 0, 256, 768);
  // 6) fused attention -> o_bf
  attn_fused<<<dim3(128, 24), 256, 0, stream>>>(q_bf, kproj, vprojT, o_bf);
  // 7) x2 = x + o @ proj_w + b -> d_out (fp32)
  gemm128<false, true, false, true><<<dim3(128, 6), 256, 0, stream>>>(
      o_bf, proj_wT, out, proj_b, x, 768, 768, 768, 768);
  // 8) LN2 (no tail blocks)
  ln768<<<16384, 256, 0, stream>>>(out, ln2_w, ln2_b, h_bf, cpartial, colsum);
  // 9) a1 = gelu(h2 @ fc1_w + b) -> big
  gemm512<true, true, true, false><<<dim3(64, 24), 512, 0, stream>>>(
      h_bf, fc1_wT, big, fc1_b, nullptr, 768, 768, 768, 3072);
  // 10) out = x2 + a1 @ fc2_w + b (in-place residual)
  gemm128<false, true, false, true><<<dim3(128, 6), 256, 0, stream>>>(
      big, fc2_wT, out, fc2_b, out, 3072, 3072, 3072, 768);
}